// Round 2
// baseline (482.098 us; speedup 1.0000x reference)
//
#include <hip/hip_runtime.h>

typedef _Float16 f16;
typedef _Float16 f16x8 __attribute__((ext_vector_type(8)));
typedef float f32x4 __attribute__((ext_vector_type(4)));

#define LDS_GL16(g, l) __builtin_amdgcn_global_load_lds( \
    (const __attribute__((address_space(1))) void*)(g),  \
    (__attribute__((address_space(3))) void*)(l), 16, 0, 0)

// ---------------- f32 -> f16 convert (n8 = n/8 threads) ----------------
__global__ __launch_bounds__(256) void conv_kern(const float* __restrict__ in,
                                                 f16* __restrict__ out, int n8) {
    int i = blockIdx.x * 256 + threadIdx.x;
    if (i >= n8) return;
    long o = (long)i * 8;
    float4 a = *(const float4*)(in + o);
    float4 b = *(const float4*)(in + o + 4);
    f16x8 v = { (f16)a.x,(f16)a.y,(f16)a.z,(f16)a.w,
                (f16)b.x,(f16)b.y,(f16)b.z,(f16)b.w };
    *(f16x8*)(out + o) = v;
}

// ---------------- RMSNorm: one block per row of 2048 (8192 rows) -----------
__global__ __launch_bounds__(256) void rmsnorm_kern(const float* __restrict__ x,
                                                    const float* __restrict__ scale,
                                                    f16* __restrict__ out) {
    long base = (long)blockIdx.x * 2048 + threadIdx.x * 8;
    float4 a = *(const float4*)(x + base);
    float4 b = *(const float4*)(x + base + 4);
    float ss = a.x*a.x + a.y*a.y + a.z*a.z + a.w*a.w
             + b.x*b.x + b.y*b.y + b.z*b.z + b.w*b.w;
    #pragma unroll
    for (int d = 1; d < 64; d <<= 1) ss += __shfl_xor(ss, d, 64);
    __shared__ float red[4];
    if ((threadIdx.x & 63) == 0) red[threadIdx.x >> 6] = ss;
    __syncthreads();
    ss = red[0] + red[1] + red[2] + red[3];
    float inv = 1.0f / (sqrtf(ss * (1.0f / 2048.0f)) + 1e-8f);
    int c = threadIdx.x * 8;
    float4 s1 = *(const float4*)(scale + c);
    float4 s2 = *(const float4*)(scale + c + 4);
    f16x8 v = { (f16)(a.x*inv*s1.x),(f16)(a.y*inv*s1.y),(f16)(a.z*inv*s1.z),(f16)(a.w*inv*s1.w),
                (f16)(b.x*inv*s2.x),(f16)(b.y*inv*s2.y),(f16)(b.z*inv*s2.z),(f16)(b.w*inv*s2.w) };
    *(f16x8*)(out + base) = v;
}

// ---------------- GEMM: C[M,N] = A[M,K] * B[N,K]^T, 128x128 tile, BK=32 ----
// EPI=0: store f16 to Ch. EPI=1: store f32 (acc + resid) to Cf.
template<int EPI>
__global__ __launch_bounds__(256, 2) void gemm_f16(
        const f16* __restrict__ A, const f16* __restrict__ B,
        f16* __restrict__ Ch, float* __restrict__ Cf,
        const float* __restrict__ resid, int M, int N, int Kd) {
    __shared__ f16 As[128 * 32];
    __shared__ f16 Bs[128 * 32];
    int nbx = N >> 7;
    int bx = blockIdx.x % nbx, by = blockIdx.x / nbx;
    int m0 = by << 7, n0 = bx << 7;
    int tid = threadIdx.x, lane = tid & 63, w = tid >> 6;
    int wr = (w >> 1) << 6, wc = (w & 1) << 6;
    int lr = lane & 15, g = lane >> 4;
    f32x4 acc[4][4] = {};
    int srow = tid >> 2, sc8 = (tid & 3) << 3;
    const f16* aA = A + (long)(m0 + srow) * Kd + sc8;
    const f16* aB = B + (long)(n0 + srow) * Kd + sc8;
    f16* lA = As + tid * 8;
    f16* lB = Bs + tid * 8;
    long strideR = (long)64 * Kd;
    for (int kt = 0; kt < Kd; kt += 32) {
        LDS_GL16(aA, lA);
        LDS_GL16(aA + strideR, lA + 2048);
        LDS_GL16(aB, lB);
        LDS_GL16(aB + strideR, lB + 2048);
        aA += 32; aB += 32;
        __syncthreads();
        f16x8 af[4], bf[4];
        #pragma unroll
        for (int i = 0; i < 4; ++i)
            af[i] = *(const f16x8*)(As + (wr + i * 16 + lr) * 32 + g * 8);
        #pragma unroll
        for (int j = 0; j < 4; ++j)
            bf[j] = *(const f16x8*)(Bs + (wc + j * 16 + lr) * 32 + g * 8);
        #pragma unroll
        for (int i = 0; i < 4; ++i)
            #pragma unroll
            for (int j = 0; j < 4; ++j)
                acc[i][j] = __builtin_amdgcn_mfma_f32_16x16x32_f16(af[i], bf[j], acc[i][j], 0, 0, 0);
        __syncthreads();
    }
    #pragma unroll
    for (int i = 0; i < 4; ++i) {
        #pragma unroll
        for (int j = 0; j < 4; ++j) {
            #pragma unroll
            for (int reg = 0; reg < 4; ++reg) {
                int row = m0 + wr + i * 16 + g * 4 + reg;
                int col = n0 + wc + j * 16 + lr;
                long idx = (long)row * N + col;
                float v = acc[i][j][reg];
                if (EPI == 0) Ch[idx] = (f16)v;
                else          Cf[idx] = v + resid[idx];
            }
        }
    }
}

// ---------------- Attention: one block per (b,l,k,h) -----------------------
// blk = ((b*32 + l)*2 + k)*16 + h.  4 waves, wave w owns rows r0=w*16 of R=64.
__global__ __launch_bounds__(256, 2) void attn_kern(
        const f16* __restrict__ Q,    // [8192, 2048]
        const f16* __restrict__ KV,   // [8192, 4096]  (k | v)
        const float* __restrict__ mask,      // [B*L*M] = [64*128]
        const float* __restrict__ bias,      // [32*16]
        float* __restrict__ attn_out,        // (B,L,K,H,R,M) f32
        f16* __restrict__ pv_out) {          // [8192, 2048]
    __shared__ f16 Vs[128 * 128];
    __shared__ f16 P[64 * 136];
    int blk = blockIdx.x;
    int h  = blk & 15;
    int bk = blk >> 4;        // (b*32+l)*2 + k   in [0,128)
    int bl = bk >> 1;         // b*32 + l         in [0,64)
    int tid = threadIdx.x, lane = tid & 63, w = tid >> 6;
    int r0 = w << 4;
    int lr = lane & 15, g = lane >> 4;
    long qbase  = (long)bk * 64 * 2048;
    long kvbase = (long)bl * 128 * 4096;
    // stage V tile (128x128 f16) linearly into LDS, 8 rounds of 256x16B
    const f16* vsrc = KV + kvbase + 2048 + h * 128;
    {
        int idx = tid;
        #pragma unroll
        for (int rnd = 0; rnd < 8; ++rnd) {
            int vrow = idx >> 4, c = idx & 15;
            LDS_GL16(vsrc + (long)vrow * 4096 + c * 8, Vs + idx * 8);
            idx += 256;
        }
    }
    // Q fragments (wave-private rows)
    f16x8 aq[4];
    const f16* qrow = Q + qbase + (long)(r0 + lr) * 2048 + h * 128 + g * 8;
    #pragma unroll
    for (int t4 = 0; t4 < 4; ++t4) aq[t4] = *(const f16x8*)(qrow + t4 * 32);
    // scores S = Q K^T  (8 col-frags x 4 k-chunks)
    f32x4 s[8] = {};
    const f16* kbase = KV + kvbase + h * 128 + g * 8;
    #pragma unroll
    for (int j = 0; j < 8; ++j) {
        #pragma unroll
        for (int t4 = 0; t4 < 4; ++t4) {
            f16x8 bkf = *(const f16x8*)(kbase + (long)(j * 16 + lr) * 4096 + t4 * 32);
            s[j] = __builtin_amdgcn_mfma_f32_16x16x32_f16(aq[t4], bkf, s[j], 0, 0, 0);
        }
    }
    // mask add (per column m = j*16+lr)
    float madd[8];
    #pragma unroll
    for (int j = 0; j < 8; ++j)
        madd[j] = (1.0f - mask[(long)bl * 128 + j * 16 + lr]) * -10000.0f;
    // rel-bias + softmax (fp32), rows r = r0 + g*4 + reg, reduce across 16 lanes
    #pragma unroll
    for (int reg = 0; reg < 4; ++reg) {
        int r = r0 + g * 4 + reg;
        float mx = -3.0e38f;
        #pragma unroll
        for (int j = 0; j < 8; ++j) {
            int m = j * 16 + lr;
            int rel = m - r;
            int bkt = (rel < -15 ? -15 : (rel > 16 ? 16 : rel)) + 15;
            float v = s[j][reg] + bias[bkt * 16 + h] + madd[j];
            s[j][reg] = v;
            mx = fmaxf(mx, v);
        }
        #pragma unroll
        for (int d = 1; d < 16; d <<= 1) mx = fmaxf(mx, __shfl_xor(mx, d, 64));
        float sum = 0.0f;
        #pragma unroll
        for (int j = 0; j < 8; ++j) {
            float e = __expf(s[j][reg] - mx);
            s[j][reg] = e;
            sum += e;
        }
        #pragma unroll
        for (int d = 1; d < 16; d <<= 1) sum += __shfl_xor(sum, d, 64);
        float inv = 1.0f / sum;
        #pragma unroll
        for (int j = 0; j < 8; ++j) s[j][reg] *= inv;
    }
    // write attn (f32 output) + P (f16, padded stride 136)
    long abase = (long)blk * 64 * 128;
    #pragma unroll
    for (int reg = 0; reg < 4; ++reg) {
        int r = r0 + g * 4 + reg;
        #pragma unroll
        for (int j = 0; j < 8; ++j) {
            attn_out[abase + (long)r * 128 + j * 16 + lr] = s[j][reg];
            P[r * 136 + j * 16 + lr] = (f16)s[j][reg];
        }
    }
    __syncthreads();   // V staged (vmcnt drained) + P visible
    // PV: out[64,128] = P[64,128] * V[128,128]
    f16x8 pa[4];
    #pragma unroll
    for (int t4 = 0; t4 < 4; ++t4)
        pa[t4] = *(const f16x8*)(P + (r0 + lr) * 136 + t4 * 32 + g * 8);
    f32x4 o[8] = {};
    #pragma unroll
    for (int dj = 0; dj < 8; ++dj) {
        #pragma unroll
        for (int t4 = 0; t4 < 4; ++t4) {
            f16x8 bv;
            #pragma unroll
            for (int rg = 0; rg < 8; ++rg)
                bv[rg] = Vs[(t4 * 32 + g * 8 + rg) * 128 + dj * 16 + lr];
            o[dj] = __builtin_amdgcn_mfma_f32_16x16x32_f16(pa[t4], bv, o[dj], 0, 0, 0);
        }
    }
    f16* ob = pv_out + qbase + h * 128;
    #pragma unroll
    for (int dj = 0; dj < 8; ++dj)
        #pragma unroll
        for (int reg = 0; reg < 4; ++reg)
            ob[(long)(r0 + g * 4 + reg) * 2048 + dj * 16 + lr] = (f16)o[dj][reg];
}

extern "C" void kernel_launch(void* const* d_in, const int* in_sizes, int n_in,
                              void* d_out, int out_size, void* d_ws, size_t ws_size,
                              hipStream_t stream) {
    const float* x     = (const float*)d_in[0];
    const float* hid   = (const float*)d_in[1];
    const float* mask  = (const float*)d_in[2];
    const float* lnsc  = (const float*)d_in[3];
    const float* q_w   = (const float*)d_in[4];
    const float* kv_w  = (const float*)d_in[5];
    const float* out_w = (const float*)d_in[6];
    const float* bias  = (const float*)d_in[7];
    float* out0 = (float*)d_out;             // (B,L,K,R,Dm) = 16,777,216 f32
    float* attn = out0 + 16777216;           // (B,L,K,H,R,M) = 16,777,216 f32

    // Scratch aliased into dead d_out regions (lifetimes are stream-ordered):
    //   kv_h  (64 MiB) -> out0 region   (dead before final GEMM writes out0)
    //   xn_h  (32 MiB) -> attn region lo (dead before attn_kern writes attn)
    //   hid_h (32 MiB) -> attn region hi (dead before attn_kern writes attn)
    f16* kv_h  = (f16*)out0;
    f16* xn_h  = (f16*)attn;
    f16* hid_h = (f16*)(attn + 8388608);
    // d_ws: 96 MiB total
    char* ws = (char*)d_ws;
    f16* q_h    = (f16*)(ws);                 // 32 MiB
    f16* ao_h   = (f16*)(ws + 33554432L);     // 32 MiB
    f16* qw_h   = (f16*)(ws + 67108864L);     //  8 MiB
    f16* kvw_h  = (f16*)(ws + 75497472L);     // 16 MiB
    f16* outw_h = (f16*)(ws + 92274688L);     //  8 MiB -> ends at 96 MiB

    conv_kern<<<2048, 256, 0, stream>>>(q_w,   qw_h,   524288);
    conv_kern<<<4096, 256, 0, stream>>>(kv_w,  kvw_h, 1048576);
    conv_kern<<<2048, 256, 0, stream>>>(out_w, outw_h, 524288);
    conv_kern<<<8192, 256, 0, stream>>>(hid,   hid_h, 2097152);
    rmsnorm_kern<<<8192, 256, 0, stream>>>(x, lnsc, xn_h);
    // q = xn * q_w^T : (8192 x 2048) = (8192 x 2048)(2048 x 2048)^T
    gemm_f16<0><<<1024, 256, 0, stream>>>(xn_h, qw_h, q_h, nullptr, nullptr,
                                          8192, 2048, 2048);
    // kv = hidden * kv_w^T : (8192 x 4096)
    gemm_f16<0><<<2048, 256, 0, stream>>>(hid_h, kvw_h, kv_h, nullptr, nullptr,
                                          8192, 4096, 2048);
    attn_kern<<<2048, 256, 0, stream>>>(q_h, kv_h, mask, bias, attn, ao_h);
    // out = ao * out_w^T + x : (8192 x 2048), f32 + residual -> d_out
    gemm_f16<1><<<1024, 256, 0, stream>>>(ao_h, outw_h, nullptr, out0, x,
                                          8192, 2048, 2048);
}

// Round 3
// 424.379 us; speedup vs baseline: 1.1360x; 1.1360x over previous
//
#include <hip/hip_runtime.h>

typedef _Float16 f16;
typedef _Float16 f16x8 __attribute__((ext_vector_type(8)));
typedef float f32x4 __attribute__((ext_vector_type(4)));

#define LDS_GL16(g, l) __builtin_amdgcn_global_load_lds( \
    (const __attribute__((address_space(1))) void*)(g),  \
    (__attribute__((address_space(3))) void*)(l), 16, 0, 0)

// ---------------- f32 -> f16 convert (n8 = n/8 threads) ----------------
__global__ __launch_bounds__(256) void conv_kern(const float* __restrict__ in,
                                                 f16* __restrict__ out, int n8) {
    int i = blockIdx.x * 256 + threadIdx.x;
    if (i >= n8) return;
    long o = (long)i * 8;
    float4 a = *(const float4*)(in + o);
    float4 b = *(const float4*)(in + o + 4);
    f16x8 v = { (f16)a.x,(f16)a.y,(f16)a.z,(f16)a.w,
                (f16)b.x,(f16)b.y,(f16)b.z,(f16)b.w };
    *(f16x8*)(out + o) = v;
}

// ---------------- RMSNorm: one block per row of 2048 (8192 rows) -----------
__global__ __launch_bounds__(256) void rmsnorm_kern(const float* __restrict__ x,
                                                    const float* __restrict__ scale,
                                                    f16* __restrict__ out) {
    long base = (long)blockIdx.x * 2048 + threadIdx.x * 8;
    float4 a = *(const float4*)(x + base);
    float4 b = *(const float4*)(x + base + 4);
    float ss = a.x*a.x + a.y*a.y + a.z*a.z + a.w*a.w
             + b.x*b.x + b.y*b.y + b.z*b.z + b.w*b.w;
    #pragma unroll
    for (int d = 1; d < 64; d <<= 1) ss += __shfl_xor(ss, d, 64);
    __shared__ float red[4];
    if ((threadIdx.x & 63) == 0) red[threadIdx.x >> 6] = ss;
    __syncthreads();
    ss = red[0] + red[1] + red[2] + red[3];
    float inv = 1.0f / (sqrtf(ss * (1.0f / 2048.0f)) + 1e-8f);
    int c = threadIdx.x * 8;
    float4 s1 = *(const float4*)(scale + c);
    float4 s2 = *(const float4*)(scale + c + 4);
    f16x8 v = { (f16)(a.x*inv*s1.x),(f16)(a.y*inv*s1.y),(f16)(a.z*inv*s1.z),(f16)(a.w*inv*s1.w),
                (f16)(b.x*inv*s2.x),(f16)(b.y*inv*s2.y),(f16)(b.z*inv*s2.z),(f16)(b.w*inv*s2.w) };
    *(f16x8*)(out + base) = v;
}

// ---------------- GEMM 256x256, BK=64, 8 waves, deep-pipelined -------------
// C[M,N] = A[M,K] * B[N,K]^T.  EPI=0: f16 out. EPI=1: f32 out + resid.
// LDS swizzle: element (row, col8) lives at row*64 + (col8 ^ (row&7))*8.
// Staging keeps LDS dest linear; global source column is inverse-swizzled.
// Pipeline: stage tile t+2 after tile-t reads; wait vmcnt(8) keeps next
// tile's 8 loads in flight across barriers (never drains in main loop).
template<int EPI>
__global__ __launch_bounds__(512, 2) void gemm256(
        const f16* __restrict__ A, const f16* __restrict__ B,
        f16* __restrict__ Ch, float* __restrict__ Cf,
        const float* __restrict__ resid, int M, int N, int Kd) {
    alignas(16) __shared__ f16 lds[65536];   // As[2]:0/16384  Bs[2]:32768/49152
    int nbx = N >> 8;
    int cpx = gridDim.x >> 3;                // blocks per XCD (grid % 8 == 0)
    int fid = (blockIdx.x & 7) * cpx + (blockIdx.x >> 3);
    int by = fid / nbx, bx = fid % nbx;
    int m0 = by << 8, n0 = bx << 8;
    int tid = threadIdx.x, lane = tid & 63, wid = tid >> 6;
    int wm = wid >> 2, wn = wid & 3, bh = wn >> 1;
    int lr = lane & 15, g = lane >> 4;

    // staging offsets: 4 rounds x (A-half{wm} + B-half{bh}), 2 loads/round
    long offA[4], offB[4]; int dA[4], dB[4];
    {
        int o16a = wn * 64 + lane;
        int o16b = ((wm << 1) | (wn & 1)) * 64 + lane;
        #pragma unroll
        for (int rd = 0; rd < 4; ++rd) {
            int oa = rd * 256 + o16a;
            int ra = wm * 128 + (oa >> 3);
            offA[rd] = (long)(m0 + ra) * Kd + (((lane & 7) ^ (ra & 7)) << 3);
            dA[rd] = wm * 8192 + oa * 8;
            int ob = rd * 256 + o16b;
            int rb = bh * 128 + (ob >> 3);
            offB[rd] = (long)(n0 + rb) * Kd + (((lane & 7) ^ (rb & 7)) << 3);
            dB[rd] = bh * 8192 + ob * 8;
        }
    }
    auto stage = [&](int kt, int p) {
        const f16* Ak = A + kt * 64;
        const f16* Bk = B + kt * 64;
        f16* la = lds + p * 16384;
        f16* lb = lds + 32768 + p * 16384;
        #pragma unroll
        for (int rd = 0; rd < 4; ++rd) {
            LDS_GL16(Ak + offA[rd], la + dA[rd]);
            LDS_GL16(Bk + offB[rd], lb + dB[rd]);
        }
    };

    f32x4 acc[8][4] = {};
    int NT = Kd >> 6;
    stage(0, 0);
    stage(1, 1);
    for (int t = 0; t < NT; ++t) {
        int p = t & 1;
        if (t + 1 < NT) asm volatile("s_waitcnt vmcnt(8)" ::: "memory");
        else            asm volatile("s_waitcnt vmcnt(0)" ::: "memory");
        __builtin_amdgcn_s_barrier();
        const f16* Ap = lds + p * 16384;
        const f16* Bp = lds + 32768 + p * 16384;
        f16x8 bf[2][4];
        #pragma unroll
        for (int kk = 0; kk < 2; ++kk)
            #pragma unroll
            for (int j = 0; j < 4; ++j) {
                int row = wn * 64 + j * 16 + lr;
                int c8 = (kk * 4 + g) ^ (row & 7);
                bf[kk][j] = *(const f16x8*)(Bp + row * 64 + c8 * 8);
            }
        #pragma unroll
        for (int q = 0; q < 4; ++q) {
            f16x8 af[2][2];
            #pragma unroll
            for (int kk = 0; kk < 2; ++kk)
                #pragma unroll
                for (int ii = 0; ii < 2; ++ii) {
                    int row = wm * 128 + (q * 2 + ii) * 16 + lr;
                    int c8 = (kk * 4 + g) ^ (row & 7);
                    af[kk][ii] = *(const f16x8*)(Ap + row * 64 + c8 * 8);
                }
            __builtin_amdgcn_s_setprio(1);
            #pragma unroll
            for (int ii = 0; ii < 2; ++ii)
                #pragma unroll
                for (int j = 0; j < 4; ++j)
                    #pragma unroll
                    for (int kk = 0; kk < 2; ++kk)
                        acc[q * 2 + ii][j] = __builtin_amdgcn_mfma_f32_16x16x32_f16(
                            af[kk][ii], bf[kk][j], acc[q * 2 + ii][j], 0, 0, 0);
            __builtin_amdgcn_s_setprio(0);
        }
        __builtin_amdgcn_s_barrier();   // reads of buf p done -> safe to overwrite
        if (t + 2 < NT) stage(t + 2, p);
    }
    #pragma unroll
    for (int i = 0; i < 8; ++i) {
        #pragma unroll
        for (int j = 0; j < 4; ++j) {
            #pragma unroll
            for (int reg = 0; reg < 4; ++reg) {
                int row = m0 + wm * 128 + i * 16 + g * 4 + reg;
                int col = n0 + wn * 64 + j * 16 + lr;
                long idx = (long)row * N + col;
                float v = acc[i][j][reg];
                if (EPI == 0) Ch[idx] = (f16)v;
                else          Cf[idx] = v + resid[idx];
            }
        }
    }
}

// ---------------- Attention: one block per (b,l,k,h) -----------------------
__global__ __launch_bounds__(256, 2) void attn_kern(
        const f16* __restrict__ Q,    // [8192, 2048]
        const f16* __restrict__ KV,   // [8192, 4096]  (k | v)
        const float* __restrict__ mask,      // [64*128]
        const float* __restrict__ bias,      // [32*16]
        float* __restrict__ attn_out,        // (B,L,K,H,R,M) f32
        f16* __restrict__ pv_out) {          // [8192, 2048]
    __shared__ f16 Vs[128 * 128];
    __shared__ f16 P[64 * 136];
    int blk = blockIdx.x;
    int h  = blk & 15;
    int bk = blk >> 4;
    int bl = bk >> 1;
    int tid = threadIdx.x, lane = tid & 63, w = tid >> 6;
    int r0 = w << 4;
    int lr = lane & 15, g = lane >> 4;
    long qbase  = (long)bk * 64 * 2048;
    long kvbase = (long)bl * 128 * 4096;
    const f16* vsrc = KV + kvbase + 2048 + h * 128;
    {
        int idx = tid;
        #pragma unroll
        for (int rnd = 0; rnd < 8; ++rnd) {
            int vrow = idx >> 4, c = idx & 15;
            LDS_GL16(vsrc + (long)vrow * 4096 + c * 8, Vs + idx * 8);
            idx += 256;
        }
    }
    f16x8 aq[4];
    const f16* qrow = Q + qbase + (long)(r0 + lr) * 2048 + h * 128 + g * 8;
    #pragma unroll
    for (int t4 = 0; t4 < 4; ++t4) aq[t4] = *(const f16x8*)(qrow + t4 * 32);
    f32x4 s[8] = {};
    const f16* kbase = KV + kvbase + h * 128 + g * 8;
    #pragma unroll
    for (int j = 0; j < 8; ++j) {
        #pragma unroll
        for (int t4 = 0; t4 < 4; ++t4) {
            f16x8 bkf = *(const f16x8*)(kbase + (long)(j * 16 + lr) * 4096 + t4 * 32);
            s[j] = __builtin_amdgcn_mfma_f32_16x16x32_f16(aq[t4], bkf, s[j], 0, 0, 0);
        }
    }
    float madd[8];
    #pragma unroll
    for (int j = 0; j < 8; ++j)
        madd[j] = (1.0f - mask[(long)bl * 128 + j * 16 + lr]) * -10000.0f;
    #pragma unroll
    for (int reg = 0; reg < 4; ++reg) {
        int r = r0 + g * 4 + reg;
        float mx = -3.0e38f;
        #pragma unroll
        for (int j = 0; j < 8; ++j) {
            int m = j * 16 + lr;
            int rel = m - r;
            int bkt = (rel < -15 ? -15 : (rel > 16 ? 16 : rel)) + 15;
            float v = s[j][reg] + bias[bkt * 16 + h] + madd[j];
            s[j][reg] = v;
            mx = fmaxf(mx, v);
        }
        #pragma unroll
        for (int d = 1; d < 16; d <<= 1) mx = fmaxf(mx, __shfl_xor(mx, d, 64));
        float sum = 0.0f;
        #pragma unroll
        for (int j = 0; j < 8; ++j) {
            float e = __expf(s[j][reg] - mx);
            s[j][reg] = e;
            sum += e;
        }
        #pragma unroll
        for (int d = 1; d < 16; d <<= 1) sum += __shfl_xor(sum, d, 64);
        float inv = 1.0f / sum;
        #pragma unroll
        for (int j = 0; j < 8; ++j) s[j][reg] *= inv;
    }
    long abase = (long)blk * 64 * 128;
    #pragma unroll
    for (int reg = 0; reg < 4; ++reg) {
        int r = r0 + g * 4 + reg;
        #pragma unroll
        for (int j = 0; j < 8; ++j) {
            attn_out[abase + (long)r * 128 + j * 16 + lr] = s[j][reg];
            P[r * 136 + j * 16 + lr] = (f16)s[j][reg];
        }
    }
    __syncthreads();
    f16x8 pa[4];
    #pragma unroll
    for (int t4 = 0; t4 < 4; ++t4)
        pa[t4] = *(const f16x8*)(P + (r0 + lr) * 136 + t4 * 32 + g * 8);
    f32x4 o[8] = {};
    #pragma unroll
    for (int dj = 0; dj < 8; ++dj) {
        #pragma unroll
        for (int t4 = 0; t4 < 4; ++t4) {
            f16x8 bv;
            #pragma unroll
            for (int rg = 0; rg < 8; ++rg)
                bv[rg] = Vs[(t4 * 32 + g * 8 + rg) * 128 + dj * 16 + lr];
            o[dj] = __builtin_amdgcn_mfma_f32_16x16x32_f16(pa[t4], bv, o[dj], 0, 0, 0);
        }
    }
    f16* ob = pv_out + qbase + h * 128;
    #pragma unroll
    for (int dj = 0; dj < 8; ++dj)
        #pragma unroll
        for (int reg = 0; reg < 4; ++reg)
            ob[(long)(r0 + g * 4 + reg) * 2048 + dj * 16 + lr] = (f16)o[dj][reg];
}

extern "C" void kernel_launch(void* const* d_in, const int* in_sizes, int n_in,
                              void* d_out, int out_size, void* d_ws, size_t ws_size,
                              hipStream_t stream) {
    const float* x     = (const float*)d_in[0];
    const float* hid   = (const float*)d_in[1];
    const float* mask  = (const float*)d_in[2];
    const float* lnsc  = (const float*)d_in[3];
    const float* q_w   = (const float*)d_in[4];
    const float* kv_w  = (const float*)d_in[5];
    const float* out_w = (const float*)d_in[6];
    const float* bias  = (const float*)d_in[7];
    float* out0 = (float*)d_out;             // (B,L,K,R,Dm) = 16,777,216 f32
    float* attn = out0 + 16777216;           // (B,L,K,H,R,M) = 16,777,216 f32

    // Scratch aliased into dead d_out regions (lifetimes stream-ordered):
    f16* kv_h  = (f16*)out0;                 // dead until final GEMM
    f16* xn_h  = (f16*)attn;                 // dead until attn_kern writes attn
    f16* hid_h = (f16*)(attn + 8388608);
    char* ws = (char*)d_ws;
    f16* q_h    = (f16*)(ws);                 // 32 MiB
    f16* ao_h   = (f16*)(ws + 33554432L);     // 32 MiB
    f16* qw_h   = (f16*)(ws + 67108864L);     //  8 MiB
    f16* kvw_h  = (f16*)(ws + 75497472L);     // 16 MiB
    f16* outw_h = (f16*)(ws + 92274688L);     //  8 MiB -> 96 MiB total

    conv_kern<<<2048, 256, 0, stream>>>(q_w,   qw_h,   524288);
    conv_kern<<<4096, 256, 0, stream>>>(kv_w,  kvw_h, 1048576);
    conv_kern<<<2048, 256, 0, stream>>>(out_w, outw_h, 524288);
    conv_kern<<<8192, 256, 0, stream>>>(hid,   hid_h, 2097152);
    rmsnorm_kern<<<8192, 256, 0, stream>>>(x, lnsc, xn_h);
    gemm256<0><<<256, 512, 0, stream>>>(xn_h, qw_h, q_h, nullptr, nullptr,
                                        8192, 2048, 2048);
    gemm256<0><<<512, 512, 0, stream>>>(hid_h, kvw_h, kv_h, nullptr, nullptr,
                                        8192, 4096, 2048);
    attn_kern<<<2048, 256, 0, stream>>>(q_h, kv_h, mask, bias, attn, ao_h);
    gemm256<1><<<256, 512, 0, stream>>>(ao_h, outw_h, nullptr, out0, x,
                                        8192, 2048, 2048);
}

// Round 4
// 403.683 us; speedup vs baseline: 1.1943x; 1.0513x over previous
//
#include <hip/hip_runtime.h>

typedef _Float16 f16;
typedef _Float16 f16x8 __attribute__((ext_vector_type(8)));
typedef float f32x4 __attribute__((ext_vector_type(4)));

#define LDS_GL16(g, l) __builtin_amdgcn_global_load_lds( \
    (const __attribute__((address_space(1))) void*)(g),  \
    (__attribute__((address_space(3))) void*)(l), 16, 0, 0)
#define VMCNT(N) asm volatile("s_waitcnt vmcnt(" #N ")" ::: "memory")
#define BAR() __builtin_amdgcn_s_barrier()

// ---------------- f32 -> f16 convert (n8 = n/8 threads) ----------------
__global__ __launch_bounds__(256) void conv_kern(const float* __restrict__ in,
                                                 f16* __restrict__ out, int n8) {
    int i = blockIdx.x * 256 + threadIdx.x;
    if (i >= n8) return;
    long o = (long)i * 8;
    float4 a = *(const float4*)(in + o);
    float4 b = *(const float4*)(in + o + 4);
    f16x8 v = { (f16)a.x,(f16)a.y,(f16)a.z,(f16)a.w,
                (f16)b.x,(f16)b.y,(f16)b.z,(f16)b.w };
    *(f16x8*)(out + o) = v;
}

// ---------------- RMSNorm: one block per row of 2048 (8192 rows) -----------
__global__ __launch_bounds__(256) void rmsnorm_kern(const float* __restrict__ x,
                                                    const float* __restrict__ scale,
                                                    f16* __restrict__ out) {
    long base = (long)blockIdx.x * 2048 + threadIdx.x * 8;
    float4 a = *(const float4*)(x + base);
    float4 b = *(const float4*)(x + base + 4);
    float ss = a.x*a.x + a.y*a.y + a.z*a.z + a.w*a.w
             + b.x*b.x + b.y*b.y + b.z*b.z + b.w*b.w;
    #pragma unroll
    for (int d = 1; d < 64; d <<= 1) ss += __shfl_xor(ss, d, 64);
    __shared__ float red[4];
    if ((threadIdx.x & 63) == 0) red[threadIdx.x >> 6] = ss;
    __syncthreads();
    ss = red[0] + red[1] + red[2] + red[3];
    float inv = 1.0f / (sqrtf(ss * (1.0f / 2048.0f)) + 1e-8f);
    int c = threadIdx.x * 8;
    float4 s1 = *(const float4*)(scale + c);
    float4 s2 = *(const float4*)(scale + c + 4);
    f16x8 v = { (f16)(a.x*inv*s1.x),(f16)(a.y*inv*s1.y),(f16)(a.z*inv*s1.z),(f16)(a.w*inv*s1.w),
                (f16)(b.x*inv*s2.x),(f16)(b.y*inv*s2.y),(f16)(b.z*inv*s2.z),(f16)(b.w*inv*s2.w) };
    *(f16x8*)(out + base) = v;
}

// ---------------- GEMM 256x256, BK=64, 8 waves, 8-phase pipelined ----------
// C[M,N] = A[M,K] * B[N,K]^T.  EPI=0: f16 out. EPI=1: f32 out + resid.
// LDS: As[2][256][64] at 0, Bs[2][256][64] at 32768 (f16 elements).
// Swizzle: logical (row,c8) stored at slot c8^(row&7); staging keeps LDS
// linear and pre-swizzles the GLOBAL source column.
// 8 phases / 2 K-tiles; gray quadrant order (00,01,11,10); each phase
// stages one 16KiB region (2 gload_lds).  Ledger: every staged region has
// >=6-phase issue-to-read lead; per-phase vmcnt(6) + double barrier.
// Regions: 0=A0 rows{0-63,128-191}, 1=B0 rows{0-31,64-95,128-159,192-223},
//          2=B1 (B0+32), 3=A1 (A0+64).
template<int EPI>
__global__ __launch_bounds__(512, 2) void gemm256(
        const f16* __restrict__ A, const f16* __restrict__ B,
        f16* __restrict__ Ch, float* __restrict__ Cf,
        const float* __restrict__ resid, int M, int N, int Kd) {
    alignas(16) __shared__ f16 lds[65536];
    int nbx = N >> 8;
    int cpx = gridDim.x >> 3;
    int fid = (blockIdx.x & 7) * cpx + (blockIdx.x >> 3);
    int by = fid / nbx, bx = fid % nbx;
    int m0 = by << 8, n0 = bx << 8;
    int tid = threadIdx.x, lane = tid & 63;
    int wid = tid >> 6, wm = wid >> 2, wn = wid & 3;
    int lr = lane & 15, g = lane >> 4;
    int iL = tid >> 3, cb = tid & 7;

    auto stage = [&](int kt, int p, int r) {
        #pragma unroll
        for (int rnd = 0; rnd < 2; ++rnd) {
            if (r == 0 || r == 3) {            // A region
                int row = iL + rnd * 128 + (r == 3 ? 64 : 0);
                LDS_GL16(A + (long)(m0 + row) * Kd + kt * 64 + ((cb ^ (row & 7)) << 3),
                         lds + p * 16384 + row * 64 + (cb << 3));
            } else {                           // B region
                int row = (iL & 31) + ((iL >> 5) + rnd * 2) * 64 + (r == 2 ? 32 : 0);
                LDS_GL16(B + (long)(n0 + row) * Kd + kt * 64 + ((cb ^ (row & 7)) << 3),
                         lds + 32768 + p * 16384 + row * 64 + (cb << 3));
            }
        }
    };

    f32x4 acc[8][4] = {};
    f16x8 a[4][2], b0[2][2], b1[2][2];

    auto loadA = [&](const f16* bp, int qm) {
        #pragma unroll
        for (int mf = 0; mf < 4; ++mf) {
            int row = wm * 128 + (qm * 4 + mf) * 16 + lr;
            #pragma unroll
            for (int kk = 0; kk < 2; ++kk)
                a[mf][kk] = *(const f16x8*)(bp + row * 64 + (((kk * 4 + g) ^ (row & 7)) << 3));
        }
    };
    auto loadB = [&](f16x8 (&d)[2][2], const f16* bp, int qn) {
        #pragma unroll
        for (int nf = 0; nf < 2; ++nf) {
            int row = wn * 64 + (qn * 2 + nf) * 16 + lr;
            #pragma unroll
            for (int kk = 0; kk < 2; ++kk)
                d[nf][kk] = *(const f16x8*)(bp + row * 64 + (((kk * 4 + g) ^ (row & 7)) << 3));
        }
    };
    auto mma = [&](f16x8 (&bb)[2][2], int qm, int qn) {
        __builtin_amdgcn_s_setprio(1);
        #pragma unroll
        for (int mf = 0; mf < 4; ++mf)
            #pragma unroll
            for (int nf = 0; nf < 2; ++nf)
                #pragma unroll
                for (int kk = 0; kk < 2; ++kk)
                    acc[qm * 4 + mf][qn * 2 + nf] = __builtin_amdgcn_mfma_f32_16x16x32_f16(
                        a[mf][kk], bb[nf][kk], acc[qm * 4 + mf][qn * 2 + nf], 0, 0, 0);
        __builtin_amdgcn_s_setprio(0);
    };

    const f16* A0p = lds;
    const f16* A1p = lds + 16384;
    const f16* B0p = lds + 32768;
    const f16* B1p = lds + 49152;
    int NT = Kd >> 6, NI = NT >> 1;

    // prologue: tile0 all 4 regions -> buf0; tile1 regions A0,B0,B1 -> buf1
    stage(0, 0, 0); stage(0, 0, 1); stage(0, 0, 2); stage(0, 0, 3);
    stage(1, 1, 0); stage(1, 1, 1); stage(1, 1, 2);
    VMCNT(6); BAR();                 // tile0 fully landed

    for (int it = 0; it < NI - 1; ++it) {
        int t0 = it * 2;
        // p1: q(0,0) tile t0 (buf0)
        loadA(A0p, 0); loadB(b0, B0p, 0);
        stage(t0 + 1, 1, 3);
        VMCNT(6); BAR(); mma(b0, 0, 0); BAR();
        // p2: q(0,1)
        loadB(b1, B0p, 1);
        stage(t0 + 2, 0, 0);
        VMCNT(6); BAR(); mma(b1, 0, 1); BAR();
        // p3: q(1,1)
        loadA(A0p, 1);
        stage(t0 + 2, 0, 1);
        VMCNT(6); BAR(); mma(b1, 1, 1); BAR();
        // p4: q(1,0)  (b0 held from p1)
        stage(t0 + 2, 0, 2);
        VMCNT(6); BAR(); mma(b0, 1, 0); BAR();
        // p5: q(0,0) tile t0+1 (buf1)
        loadA(A1p, 0); loadB(b0, B1p, 0);
        stage(t0 + 2, 0, 3);
        VMCNT(6); BAR(); mma(b0, 0, 0); BAR();
        // p6
        loadB(b1, B1p, 1);
        stage(t0 + 3, 1, 0);
        VMCNT(6); BAR(); mma(b1, 0, 1); BAR();
        // p7
        loadA(A1p, 1);
        stage(t0 + 3, 1, 1);
        VMCNT(6); BAR(); mma(b1, 1, 1); BAR();
        // p8
        stage(t0 + 3, 1, 2);
        VMCNT(6); BAR(); mma(b0, 1, 0); BAR();
    }
    {   // final iteration: only p1 stages (tile NT-1 region A1)
        loadA(A0p, 0); loadB(b0, B0p, 0);
        stage(NT - 1, 1, 3);
        VMCNT(6); BAR(); mma(b0, 0, 0); BAR();
        loadB(b1, B0p, 1);
        VMCNT(6); BAR(); mma(b1, 0, 1); BAR();
        loadA(A0p, 1);
        VMCNT(6); BAR(); mma(b1, 1, 1); BAR();
        VMCNT(4); BAR(); mma(b0, 1, 0); BAR();
        loadA(A1p, 0); loadB(b0, B1p, 0);
        VMCNT(2); BAR(); mma(b0, 0, 0); BAR();
        loadB(b1, B1p, 1);
        VMCNT(0); BAR(); mma(b1, 0, 1); BAR();
        loadA(A1p, 1);
        BAR(); mma(b1, 1, 1); BAR();
        BAR(); mma(b0, 1, 0); BAR();
    }

    #pragma unroll
    for (int i = 0; i < 8; ++i) {
        #pragma unroll
        for (int j = 0; j < 4; ++j) {
            #pragma unroll
            for (int reg = 0; reg < 4; ++reg) {
                int row = m0 + wm * 128 + i * 16 + g * 4 + reg;
                int col = n0 + wn * 64 + j * 16 + lr;
                long idx = (long)row * N + col;
                float v = acc[i][j][reg];
                if (EPI == 0) Ch[idx] = (f16)v;
                else          Cf[idx] = v + resid[idx];
            }
        }
    }
}

// ---------------- Attention: one block per (b,l,k,h) -----------------------
__global__ __launch_bounds__(256, 2) void attn_kern(
        const f16* __restrict__ Q,    // [8192, 2048]
        const f16* __restrict__ KV,   // [8192, 4096]  (k | v)
        const float* __restrict__ mask,      // [64*128]
        const float* __restrict__ bias,      // [32*16]
        float* __restrict__ attn_out,        // (B,L,K,H,R,M) f32
        f16* __restrict__ pv_out) {          // [8192, 2048]
    __shared__ f16 Vs[128 * 128];
    __shared__ f16 P[64 * 136];
    int blk = blockIdx.x;
    int h  = blk & 15;
    int bk = blk >> 4;
    int bl = bk >> 1;
    int tid = threadIdx.x, lane = tid & 63, w = tid >> 6;
    int r0 = w << 4;
    int lr = lane & 15, g = lane >> 4;
    long qbase  = (long)bk * 64 * 2048;
    long kvbase = (long)bl * 128 * 4096;
    const f16* vsrc = KV + kvbase + 2048 + h * 128;
    {
        int idx = tid;
        #pragma unroll
        for (int rnd = 0; rnd < 8; ++rnd) {
            int vrow = idx >> 4, c = idx & 15;
            LDS_GL16(vsrc + (long)vrow * 4096 + c * 8, Vs + idx * 8);
            idx += 256;
        }
    }
    f16x8 aq[4];
    const f16* qrow = Q + qbase + (long)(r0 + lr) * 2048 + h * 128 + g * 8;
    #pragma unroll
    for (int t4 = 0; t4 < 4; ++t4) aq[t4] = *(const f16x8*)(qrow + t4 * 32);
    f32x4 s[8] = {};
    const f16* kbase = KV + kvbase + h * 128 + g * 8;
    #pragma unroll
    for (int j = 0; j < 8; ++j) {
        #pragma unroll
        for (int t4 = 0; t4 < 4; ++t4) {
            f16x8 bkf = *(const f16x8*)(kbase + (long)(j * 16 + lr) * 4096 + t4 * 32);
            s[j] = __builtin_amdgcn_mfma_f32_16x16x32_f16(aq[t4], bkf, s[j], 0, 0, 0);
        }
    }
    float madd[8];
    #pragma unroll
    for (int j = 0; j < 8; ++j)
        madd[j] = (1.0f - mask[(long)bl * 128 + j * 16 + lr]) * -10000.0f;
    #pragma unroll
    for (int reg = 0; reg < 4; ++reg) {
        int r = r0 + g * 4 + reg;
        float mx = -3.0e38f;
        #pragma unroll
        for (int j = 0; j < 8; ++j) {
            int m = j * 16 + lr;
            int rel = m - r;
            int bkt = (rel < -15 ? -15 : (rel > 16 ? 16 : rel)) + 15;
            float v = s[j][reg] + bias[bkt * 16 + h] + madd[j];
            s[j][reg] = v;
            mx = fmaxf(mx, v);
        }
        #pragma unroll
        for (int d = 1; d < 16; d <<= 1) mx = fmaxf(mx, __shfl_xor(mx, d, 64));
        float sum = 0.0f;
        #pragma unroll
        for (int j = 0; j < 8; ++j) {
            float e = __expf(s[j][reg] - mx);
            s[j][reg] = e;
            sum += e;
        }
        #pragma unroll
        for (int d = 1; d < 16; d <<= 1) sum += __shfl_xor(sum, d, 64);
        float inv = 1.0f / sum;
        #pragma unroll
        for (int j = 0; j < 8; ++j) s[j][reg] *= inv;
    }
    long abase = (long)blk * 64 * 128;
    #pragma unroll
    for (int reg = 0; reg < 4; ++reg) {
        int r = r0 + g * 4 + reg;
        #pragma unroll
        for (int j = 0; j < 8; ++j) {
            attn_out[abase + (long)r * 128 + j * 16 + lr] = s[j][reg];
            P[r * 136 + j * 16 + lr] = (f16)s[j][reg];
        }
    }
    __syncthreads();
    f16x8 pa[4];
    #pragma unroll
    for (int t4 = 0; t4 < 4; ++t4)
        pa[t4] = *(const f16x8*)(P + (r0 + lr) * 136 + t4 * 32 + g * 8);
    f32x4 o[8] = {};
    #pragma unroll
    for (int dj = 0; dj < 8; ++dj) {
        #pragma unroll
        for (int t4 = 0; t4 < 4; ++t4) {
            f16x8 bv;
            #pragma unroll
            for (int rg = 0; rg < 8; ++rg)
                bv[rg] = Vs[(t4 * 32 + g * 8 + rg) * 128 + dj * 16 + lr];
            o[dj] = __builtin_amdgcn_mfma_f32_16x16x32_f16(pa[t4], bv, o[dj], 0, 0, 0);
        }
    }
    f16* ob = pv_out + qbase + h * 128;
    #pragma unroll
    for (int dj = 0; dj < 8; ++dj)
        #pragma unroll
        for (int reg = 0; reg < 4; ++reg)
            ob[(long)(r0 + g * 4 + reg) * 2048 + dj * 16 + lr] = (f16)o[dj][reg];
}

extern "C" void kernel_launch(void* const* d_in, const int* in_sizes, int n_in,
                              void* d_out, int out_size, void* d_ws, size_t ws_size,
                              hipStream_t stream) {
    const float* x     = (const float*)d_in[0];
    const float* hid   = (const float*)d_in[1];
    const float* mask  = (const float*)d_in[2];
    const float* lnsc  = (const float*)d_in[3];
    const float* q_w   = (const float*)d_in[4];
    const float* kv_w  = (const float*)d_in[5];
    const float* out_w = (const float*)d_in[6];
    const float* bias  = (const float*)d_in[7];
    float* out0 = (float*)d_out;             // (B,L,K,R,Dm) = 16,777,216 f32
    float* attn = out0 + 16777216;           // (B,L,K,H,R,M) = 16,777,216 f32

    // Scratch aliased into dead d_out regions (lifetimes stream-ordered):
    f16* kv_h  = (f16*)out0;                 // dead until final GEMM
    f16* xn_h  = (f16*)attn;                 // dead until attn_kern writes attn
    f16* hid_h = (f16*)(attn + 8388608);
    char* ws = (char*)d_ws;
    f16* q_h    = (f16*)(ws);                 // 32 MiB
    f16* ao_h   = (f16*)(ws + 33554432L);     // 32 MiB
    f16* qw_h   = (f16*)(ws + 67108864L);     //  8 MiB
    f16* kvw_h  = (f16*)(ws + 75497472L);     // 16 MiB
    f16* outw_h = (f16*)(ws + 92274688L);     //  8 MiB -> 96 MiB total

    conv_kern<<<2048, 256, 0, stream>>>(q_w,   qw_h,   524288);
    conv_kern<<<4096, 256, 0, stream>>>(kv_w,  kvw_h, 1048576);
    conv_kern<<<2048, 256, 0, stream>>>(out_w, outw_h, 524288);
    conv_kern<<<8192, 256, 0, stream>>>(hid,   hid_h, 2097152);
    rmsnorm_kern<<<8192, 256, 0, stream>>>(x, lnsc, xn_h);
    gemm256<0><<<256, 512, 0, stream>>>(xn_h, qw_h, q_h, nullptr, nullptr,
                                        8192, 2048, 2048);
    gemm256<0><<<512, 512, 0, stream>>>(hid_h, kvw_h, kv_h, nullptr, nullptr,
                                        8192, 4096, 2048);
    attn_kern<<<2048, 256, 0, stream>>>(q_h, kv_h, mask, bias, attn, ao_h);
    gemm256<1><<<256, 512, 0, stream>>>(ao_h, outw_h, nullptr, out0, x,
                                        8192, 2048, 2048);
}

// Round 5
// 396.961 us; speedup vs baseline: 1.2145x; 1.0169x over previous
//
#include <hip/hip_runtime.h>

typedef _Float16 f16;
typedef _Float16 f16x8 __attribute__((ext_vector_type(8)));
typedef float f32x4 __attribute__((ext_vector_type(4)));

#define LDS_GL16(g, l) __builtin_amdgcn_global_load_lds( \
    (const __attribute__((address_space(1))) void*)(g),  \
    (__attribute__((address_space(3))) void*)(l), 16, 0, 0)
#define VMCNT(N) asm volatile("s_waitcnt vmcnt(" #N ")" ::: "memory")
#define BAR() __builtin_amdgcn_s_barrier()

// ------- segmented f32 -> f16 convert: 4 buffers in one launch -------------
// seg sizes in blocks: qw 2048 | kvw 4096 | outw 2048 | hid 8192  (16384 total)
__global__ __launch_bounds__(256) void conv4_kern(
        const float* __restrict__ s0, f16* __restrict__ d0,
        const float* __restrict__ s1, f16* __restrict__ d1,
        const float* __restrict__ s2, f16* __restrict__ d2,
        const float* __restrict__ s3, f16* __restrict__ d3) {
    int b = blockIdx.x;
    const float* in; f16* out; long base;
    if (b < 2048)       { in = s0; out = d0; base = (long)b * 2048; }
    else if (b < 6144)  { in = s1; out = d1; base = (long)(b - 2048) * 2048; }
    else if (b < 8192)  { in = s2; out = d2; base = (long)(b - 6144) * 2048; }
    else                { in = s3; out = d3; base = (long)(b - 8192) * 2048; }
    long o = base + threadIdx.x * 8;
    float4 a = *(const float4*)(in + o);
    float4 c = *(const float4*)(in + o + 4);
    f16x8 v = { (f16)a.x,(f16)a.y,(f16)a.z,(f16)a.w,
                (f16)c.x,(f16)c.y,(f16)c.z,(f16)c.w };
    *(f16x8*)(out + o) = v;
}

// ---------------- RMSNorm: one block per row of 2048 (8192 rows) -----------
__global__ __launch_bounds__(256) void rmsnorm_kern(const float* __restrict__ x,
                                                    const float* __restrict__ scale,
                                                    f16* __restrict__ out) {
    long base = (long)blockIdx.x * 2048 + threadIdx.x * 8;
    float4 a = *(const float4*)(x + base);
    float4 b = *(const float4*)(x + base + 4);
    float ss = a.x*a.x + a.y*a.y + a.z*a.z + a.w*a.w
             + b.x*b.x + b.y*b.y + b.z*b.z + b.w*b.w;
    #pragma unroll
    for (int d = 1; d < 64; d <<= 1) ss += __shfl_xor(ss, d, 64);
    __shared__ float red[4];
    if ((threadIdx.x & 63) == 0) red[threadIdx.x >> 6] = ss;
    __syncthreads();
    ss = red[0] + red[1] + red[2] + red[3];
    float inv = 1.0f / (sqrtf(ss * (1.0f / 2048.0f)) + 1e-8f);
    int c = threadIdx.x * 8;
    float4 s1 = *(const float4*)(scale + c);
    float4 s2 = *(const float4*)(scale + c + 4);
    f16x8 v = { (f16)(a.x*inv*s1.x),(f16)(a.y*inv*s1.y),(f16)(a.z*inv*s1.z),(f16)(a.w*inv*s1.w),
                (f16)(b.x*inv*s2.x),(f16)(b.y*inv*s2.y),(f16)(b.z*inv*s2.z),(f16)(b.w*inv*s2.w) };
    *(f16x8*)(out + base) = v;
}

// ---------------- GEMM 256x256, BK=64, 8 waves, 8-phase pipelined ----------
// C[M,N] = A[M,K] * B[N,K]^T.  EPI=0: f16 out. EPI=1: f32 out + resid.
// vmcnt(6) ONLY at p4/p8 (m201 discipline).  Ledger (per-thread loads, 2 per
// stage): after prologue 6 in flight {t1:A0,B0,B1}.  At it p4, drain-to-6
// lands {t0+1:A0,B0,B1,A1}; at p8 lands {t0+2:A0,B0,B1,A1}.  Every stage
// trails its region's last reader by >=1 barrier (WAR-safe).
template<int EPI>
__global__ __launch_bounds__(512, 2) void gemm256(
        const f16* __restrict__ A, const f16* __restrict__ B,
        f16* __restrict__ Ch, float* __restrict__ Cf,
        const float* __restrict__ resid, int M, int N, int Kd) {
    alignas(16) __shared__ f16 lds[65536];
    int nbx = N >> 8;
    int cpx = gridDim.x >> 3;
    int fid = (blockIdx.x & 7) * cpx + (blockIdx.x >> 3);
    int by = fid / nbx, bx = fid % nbx;
    int m0 = by << 8, n0 = bx << 8;
    int tid = threadIdx.x, lane = tid & 63;
    int wid = tid >> 6, wm = wid >> 2, wn = wid & 3;
    int lr = lane & 15, g = lane >> 4;
    int iL = tid >> 3, cb = tid & 7;

    auto stage = [&](int kt, int p, int r) {
        #pragma unroll
        for (int rnd = 0; rnd < 2; ++rnd) {
            if (r == 0 || r == 3) {            // A region
                int row = iL + rnd * 128 + (r == 3 ? 64 : 0);
                LDS_GL16(A + (long)(m0 + row) * Kd + kt * 64 + ((cb ^ (row & 7)) << 3),
                         lds + p * 16384 + row * 64 + (cb << 3));
            } else {                           // B region
                int row = (iL & 31) + ((iL >> 5) + rnd * 2) * 64 + (r == 2 ? 32 : 0);
                LDS_GL16(B + (long)(n0 + row) * Kd + kt * 64 + ((cb ^ (row & 7)) << 3),
                         lds + 32768 + p * 16384 + row * 64 + (cb << 3));
            }
        }
    };

    f32x4 acc[8][4] = {};
    f16x8 a[4][2], b0[2][2], b1[2][2];

    auto loadA = [&](const f16* bp, int qm) {
        #pragma unroll
        for (int mf = 0; mf < 4; ++mf) {
            int row = wm * 128 + (qm * 4 + mf) * 16 + lr;
            #pragma unroll
            for (int kk = 0; kk < 2; ++kk)
                a[mf][kk] = *(const f16x8*)(bp + row * 64 + (((kk * 4 + g) ^ (row & 7)) << 3));
        }
    };
    auto loadB = [&](f16x8 (&d)[2][2], const f16* bp, int qn) {
        #pragma unroll
        for (int nf = 0; nf < 2; ++nf) {
            int row = wn * 64 + (qn * 2 + nf) * 16 + lr;
            #pragma unroll
            for (int kk = 0; kk < 2; ++kk)
                d[nf][kk] = *(const f16x8*)(bp + row * 64 + (((kk * 4 + g) ^ (row & 7)) << 3));
        }
    };
    auto mma = [&](f16x8 (&bb)[2][2], int qm, int qn) {
        __builtin_amdgcn_s_setprio(1);
        #pragma unroll
        for (int mf = 0; mf < 4; ++mf)
            #pragma unroll
            for (int nf = 0; nf < 2; ++nf)
                #pragma unroll
                for (int kk = 0; kk < 2; ++kk)
                    acc[qm * 4 + mf][qn * 2 + nf] = __builtin_amdgcn_mfma_f32_16x16x32_f16(
                        a[mf][kk], bb[nf][kk], acc[qm * 4 + mf][qn * 2 + nf], 0, 0, 0);
        __builtin_amdgcn_s_setprio(0);
    };

    const f16* A0p = lds;
    const f16* A1p = lds + 16384;
    const f16* B0p = lds + 32768;
    const f16* B1p = lds + 49152;
    int NT = Kd >> 6, NI = NT >> 1;

    // prologue: tile0 all 4 regions -> buf0; tile1 A0,B0,B1 -> buf1
    stage(0, 0, 0); stage(0, 0, 1); stage(0, 0, 2); stage(0, 0, 3);
    stage(1, 1, 0); stage(1, 1, 1); stage(1, 1, 2);
    VMCNT(6); BAR();                 // tile0 landed; 6 in flight

    for (int it = 0; it < NI - 1; ++it) {
        int t0 = it * 2;
        // p1: q(0,0) tile t0 (buf0)
        loadA(A0p, 0); loadB(b0, B0p, 0);
        stage(t0 + 1, 1, 3);
        BAR(); mma(b0, 0, 0); BAR();
        // p2: q(0,1)
        loadB(b1, B0p, 1);
        stage(t0 + 2, 0, 0);
        BAR(); mma(b1, 0, 1); BAR();
        // p3: q(1,1)
        loadA(A0p, 1);
        stage(t0 + 2, 0, 1);
        BAR(); mma(b1, 1, 1); BAR();
        // p4: q(1,0)  (b0 held from p1)
        stage(t0 + 2, 0, 2);
        VMCNT(6);                    // lands tile t0+1 completely
        BAR(); mma(b0, 1, 0); BAR();
        // p5: q(0,0) tile t0+1 (buf1)
        loadA(A1p, 0); loadB(b0, B1p, 0);
        stage(t0 + 2, 0, 3);
        BAR(); mma(b0, 0, 0); BAR();
        // p6
        loadB(b1, B1p, 1);
        stage(t0 + 3, 1, 0);
        BAR(); mma(b1, 0, 1); BAR();
        // p7
        loadA(A1p, 1);
        stage(t0 + 3, 1, 1);
        BAR(); mma(b1, 1, 1); BAR();
        // p8
        stage(t0 + 3, 1, 2);
        VMCNT(6);                    // lands tile t0+2 completely
        BAR(); mma(b0, 1, 0); BAR();
    }
    {   // final iteration (tiles NT-2, NT-1): only p1 stages
        loadA(A0p, 0); loadB(b0, B0p, 0);
        stage(NT - 1, 1, 3);
        BAR(); mma(b0, 0, 0); BAR();
        loadB(b1, B0p, 1);
        BAR(); mma(b1, 0, 1); BAR();
        loadA(A0p, 1);
        BAR(); mma(b1, 1, 1); BAR();
        VMCNT(0);                    // tile NT-1 fully landed
        BAR(); mma(b0, 1, 0); BAR();
        loadA(A1p, 0); loadB(b0, B1p, 0);
        BAR(); mma(b0, 0, 0); BAR();
        loadB(b1, B1p, 1);
        BAR(); mma(b1, 0, 1); BAR();
        loadA(A1p, 1);
        BAR(); mma(b1, 1, 1); BAR();
        BAR(); mma(b0, 1, 0);
    }

    #pragma unroll
    for (int i = 0; i < 8; ++i) {
        #pragma unroll
        for (int j = 0; j < 4; ++j) {
            #pragma unroll
            for (int reg = 0; reg < 4; ++reg) {
                int row = m0 + wm * 128 + i * 16 + g * 4 + reg;
                int col = n0 + wn * 64 + j * 16 + lr;
                long idx = (long)row * N + col;
                float v = acc[i][j][reg];
                if (EPI == 0) Ch[idx] = (f16)v;
                else          Cf[idx] = v + resid[idx];
            }
        }
    }
}

// ---------------- Attention: one block per (b,l,k,h) -----------------------
__global__ __launch_bounds__(256, 2) void attn_kern(
        const f16* __restrict__ Q,    // [8192, 2048]
        const f16* __restrict__ KV,   // [8192, 4096]  (k | v)
        const float* __restrict__ mask,      // [64*128]
        const float* __restrict__ bias,      // [32*16]
        float* __restrict__ attn_out,        // (B,L,K,H,R,M) f32
        f16* __restrict__ pv_out) {          // [8192, 2048]
    __shared__ f16 Vs[128 * 128];
    __shared__ f16 P[64 * 136];
    int blk = blockIdx.x;
    int h  = blk & 15;
    int bk = blk >> 4;
    int bl = bk >> 1;
    int tid = threadIdx.x, lane = tid & 63, w = tid >> 6;
    int r0 = w << 4;
    int lr = lane & 15, g = lane >> 4;
    long qbase  = (long)bk * 64 * 2048;
    long kvbase = (long)bl * 128 * 4096;
    const f16* vsrc = KV + kvbase + 2048 + h * 128;
    {
        int idx = tid;
        #pragma unroll
        for (int rnd = 0; rnd < 8; ++rnd) {
            int vrow = idx >> 4, c = idx & 15;
            LDS_GL16(vsrc + (long)vrow * 4096 + c * 8, Vs + idx * 8);
            idx += 256;
        }
    }
    f16x8 aq[4];
    const f16* qrow = Q + qbase + (long)(r0 + lr) * 2048 + h * 128 + g * 8;
    #pragma unroll
    for (int t4 = 0; t4 < 4; ++t4) aq[t4] = *(const f16x8*)(qrow + t4 * 32);
    f32x4 s[8] = {};
    const f16* kbase = KV + kvbase + h * 128 + g * 8;
    #pragma unroll
    for (int j = 0; j < 8; ++j) {
        #pragma unroll
        for (int t4 = 0; t4 < 4; ++t4) {
            f16x8 bkf = *(const f16x8*)(kbase + (long)(j * 16 + lr) * 4096 + t4 * 32);
            s[j] = __builtin_amdgcn_mfma_f32_16x16x32_f16(aq[t4], bkf, s[j], 0, 0, 0);
        }
    }
    float madd[8];
    #pragma unroll
    for (int j = 0; j < 8; ++j)
        madd[j] = (1.0f - mask[(long)bl * 128 + j * 16 + lr]) * -10000.0f;
    #pragma unroll
    for (int reg = 0; reg < 4; ++reg) {
        int r = r0 + g * 4 + reg;
        float mx = -3.0e38f;
        #pragma unroll
        for (int j = 0; j < 8; ++j) {
            int m = j * 16 + lr;
            int rel = m - r;
            int bkt = (rel < -15 ? -15 : (rel > 16 ? 16 : rel)) + 15;
            float v = s[j][reg] + bias[bkt * 16 + h] + madd[j];
            s[j][reg] = v;
            mx = fmaxf(mx, v);
        }
        #pragma unroll
        for (int d = 1; d < 16; d <<= 1) mx = fmaxf(mx, __shfl_xor(mx, d, 64));
        float sum = 0.0f;
        #pragma unroll
        for (int j = 0; j < 8; ++j) {
            float e = __expf(s[j][reg] - mx);
            s[j][reg] = e;
            sum += e;
        }
        #pragma unroll
        for (int d = 1; d < 16; d <<= 1) sum += __shfl_xor(sum, d, 64);
        float inv = 1.0f / sum;
        #pragma unroll
        for (int j = 0; j < 8; ++j) s[j][reg] *= inv;
    }
    long abase = (long)blk * 64 * 128;
    #pragma unroll
    for (int reg = 0; reg < 4; ++reg) {
        int r = r0 + g * 4 + reg;
        #pragma unroll
        for (int j = 0; j < 8; ++j) {
            attn_out[abase + (long)r * 128 + j * 16 + lr] = s[j][reg];
            P[r * 136 + j * 16 + lr] = (f16)s[j][reg];
        }
    }
    __syncthreads();
    f16x8 pa[4];
    #pragma unroll
    for (int t4 = 0; t4 < 4; ++t4)
        pa[t4] = *(const f16x8*)(P + (r0 + lr) * 136 + t4 * 32 + g * 8);
    f32x4 o[8] = {};
    #pragma unroll
    for (int dj = 0; dj < 8; ++dj) {
        #pragma unroll
        for (int t4 = 0; t4 < 4; ++t4) {
            f16x8 bv;
            #pragma unroll
            for (int rg = 0; rg < 8; ++rg)
                bv[rg] = Vs[(t4 * 32 + g * 8 + rg) * 128 + dj * 16 + lr];
            o[dj] = __builtin_amdgcn_mfma_f32_16x16x32_f16(pa[t4], bv, o[dj], 0, 0, 0);
        }
    }
    f16* ob = pv_out + qbase + h * 128;
    #pragma unroll
    for (int dj = 0; dj < 8; ++dj)
        #pragma unroll
        for (int reg = 0; reg < 4; ++reg)
            ob[(long)(r0 + g * 4 + reg) * 2048 + dj * 16 + lr] = (f16)o[dj][reg];
}

extern "C" void kernel_launch(void* const* d_in, const int* in_sizes, int n_in,
                              void* d_out, int out_size, void* d_ws, size_t ws_size,
                              hipStream_t stream) {
    const float* x     = (const float*)d_in[0];
    const float* hid   = (const float*)d_in[1];
    const float* mask  = (const float*)d_in[2];
    const float* lnsc  = (const float*)d_in[3];
    const float* q_w   = (const float*)d_in[4];
    const float* kv_w  = (const float*)d_in[5];
    const float* out_w = (const float*)d_in[6];
    const float* bias  = (const float*)d_in[7];
    float* out0 = (float*)d_out;             // (B,L,K,R,Dm) = 16,777,216 f32
    float* attn = out0 + 16777216;           // (B,L,K,H,R,M) = 16,777,216 f32

    // Scratch aliased into dead d_out regions (lifetimes stream-ordered):
    f16* kv_h  = (f16*)out0;                 // dead until final GEMM
    f16* xn_h  = (f16*)attn;                 // dead until attn_kern writes attn
    f16* hid_h = (f16*)(attn + 8388608);
    char* ws = (char*)d_ws;
    f16* q_h    = (f16*)(ws);                 // 32 MiB
    f16* ao_h   = (f16*)(ws + 33554432L);     // 32 MiB
    f16* qw_h   = (f16*)(ws + 67108864L);     //  8 MiB
    f16* kvw_h  = (f16*)(ws + 75497472L);     // 16 MiB
    f16* outw_h = (f16*)(ws + 92274688L);     //  8 MiB -> 96 MiB total

    conv4_kern<<<16384, 256, 0, stream>>>(q_w, qw_h, kv_w, kvw_h,
                                          out_w, outw_h, hid, hid_h);
    rmsnorm_kern<<<8192, 256, 0, stream>>>(x, lnsc, xn_h);
    gemm256<0><<<256, 512, 0, stream>>>(xn_h, qw_h, q_h, nullptr, nullptr,
                                        8192, 2048, 2048);
    gemm256<0><<<512, 512, 0, stream>>>(hid_h, kvw_h, kv_h, nullptr, nullptr,
                                        8192, 4096, 2048);
    attn_kern<<<2048, 256, 0, stream>>>(q_h, kv_h, mask, bias, attn, ao_h);
    gemm256<1><<<256, 512, 0, stream>>>(ao_h, outw_h, nullptr, out0, x,
                                        8192, 2048, 2048);
}

// Round 6
// 385.246 us; speedup vs baseline: 1.2514x; 1.0304x over previous
//
#include <hip/hip_runtime.h>

typedef _Float16 f16;
typedef _Float16 f16x8 __attribute__((ext_vector_type(8)));
typedef float f32x4 __attribute__((ext_vector_type(4)));

#define LDS_GL16(g, l) __builtin_amdgcn_global_load_lds( \
    (const __attribute__((address_space(1))) void*)(g),  \
    (__attribute__((address_space(3))) void*)(l), 16, 0, 0)
#define VMCNT(N) asm volatile("s_waitcnt vmcnt(" #N ")" ::: "memory")
#define BAR() __builtin_amdgcn_s_barrier()

// ------- segmented f32 -> f16 convert: 4 buffers in one launch -------------
__global__ __launch_bounds__(256) void conv4_kern(
        const float* __restrict__ s0, f16* __restrict__ d0,
        const float* __restrict__ s1, f16* __restrict__ d1,
        const float* __restrict__ s2, f16* __restrict__ d2,
        const float* __restrict__ s3, f16* __restrict__ d3) {
    int b = blockIdx.x;
    const float* in; f16* out; long base;
    if (b < 2048)       { in = s0; out = d0; base = (long)b * 2048; }
    else if (b < 6144)  { in = s1; out = d1; base = (long)(b - 2048) * 2048; }
    else if (b < 8192)  { in = s2; out = d2; base = (long)(b - 6144) * 2048; }
    else                { in = s3; out = d3; base = (long)(b - 8192) * 2048; }
    long o = base + threadIdx.x * 8;
    float4 a = *(const float4*)(in + o);
    float4 c = *(const float4*)(in + o + 4);
    f16x8 v = { (f16)a.x,(f16)a.y,(f16)a.z,(f16)a.w,
                (f16)c.x,(f16)c.y,(f16)c.z,(f16)c.w };
    *(f16x8*)(out + o) = v;
}

// ---------------- RMSNorm: one block per row of 2048 (8192 rows) -----------
__global__ __launch_bounds__(256) void rmsnorm_kern(const float* __restrict__ x,
                                                    const float* __restrict__ scale,
                                                    f16* __restrict__ out) {
    long base = (long)blockIdx.x * 2048 + threadIdx.x * 8;
    float4 a = *(const float4*)(x + base);
    float4 b = *(const float4*)(x + base + 4);
    float ss = a.x*a.x + a.y*a.y + a.z*a.z + a.w*a.w
             + b.x*b.x + b.y*b.y + b.z*b.z + b.w*b.w;
    #pragma unroll
    for (int d = 1; d < 64; d <<= 1) ss += __shfl_xor(ss, d, 64);
    __shared__ float red[4];
    if ((threadIdx.x & 63) == 0) red[threadIdx.x >> 6] = ss;
    __syncthreads();
    ss = red[0] + red[1] + red[2] + red[3];
    float inv = 1.0f / (sqrtf(ss * (1.0f / 2048.0f)) + 1e-8f);
    int c = threadIdx.x * 8;
    float4 s1 = *(const float4*)(scale + c);
    float4 s2 = *(const float4*)(scale + c + 4);
    f16x8 v = { (f16)(a.x*inv*s1.x),(f16)(a.y*inv*s1.y),(f16)(a.z*inv*s1.z),(f16)(a.w*inv*s1.w),
                (f16)(b.x*inv*s2.x),(f16)(b.y*inv*s2.y),(f16)(b.z*inv*s2.z),(f16)(b.w*inv*s2.w) };
    *(f16x8*)(out + base) = v;
}

// ---------------- GEMM 256x256, BK=64, 8 waves, 8-phase pipelined ----------
// C[M,N] = A[M,K] * B[N,K]^T.  EPI=0: f16 out. EPI=1: f32 out + resid.
// Affine LDS addressing: fragment row&7 == lr&7 always, so the XOR-swizzle
// term is per-lane constant; all ds_reads are base[kk] + literal offset.
// LDS bytes: A buf p at p*32768; B buf p at 65536 + p*32768.
template<int EPI>
__global__ __launch_bounds__(512, 2) void gemm256(
        const f16* __restrict__ A, const f16* __restrict__ B,
        f16* __restrict__ Ch, float* __restrict__ Cf,
        const float* __restrict__ resid, int M, int N, int Kd) {
    alignas(16) __shared__ f16 lds[65536];
    int nbx = N >> 8;
    int cpx = gridDim.x >> 3;
    int fid = (blockIdx.x & 7) * cpx + (blockIdx.x >> 3);
    int by = fid / nbx, bx = fid % nbx;
    int m0 = by << 8, n0 = bx << 8;
    int tid = threadIdx.x, lane = tid & 63;
    int wid = tid >> 6, wm = wid >> 2, wn = wid & 3;
    int lr = lane & 15, g = lane >> 4;
    int iL = tid >> 3, cb = tid & 7;

    // ---- staging offsets precomputed once (8 slots = 4 regions x 2 rounds)
    // regions: 0 = A rows {iL, iL+128}; 1 = B rows {(iL&31)+(iL>>5)*64, +128}
    //          2 = region1 + 32; 3 = region0 + 64
    long goff[8]; int doff[8];
    {
        #pragma unroll
        for (int rd = 0; rd < 2; ++rd) {
            int rA0 = iL + rd * 128;
            goff[0 + rd] = (long)(m0 + rA0) * Kd + ((cb ^ (rA0 & 7)) << 3);
            doff[0 + rd] = rA0 * 64 + cb * 8;
            int rB0 = (iL & 31) + ((iL >> 5) + rd * 2) * 64;
            goff[2 + rd] = (long)(n0 + rB0) * Kd + ((cb ^ (rB0 & 7)) << 3);
            doff[2 + rd] = 32768 + rB0 * 64 + cb * 8;
            int rB1 = rB0 + 32;
            goff[4 + rd] = (long)(n0 + rB1) * Kd + ((cb ^ (rB1 & 7)) << 3);
            doff[4 + rd] = 32768 + rB1 * 64 + cb * 8;
            int rA1 = rA0 + 64;
            goff[6 + rd] = (long)(m0 + rA1) * Kd + ((cb ^ (rA1 & 7)) << 3);
            doff[6 + rd] = rA1 * 64 + cb * 8;
        }
    }
    auto stage = [&](int kt, int p, int r) {
        const f16* src = (r == 0 || r == 3) ? A : B;
        #pragma unroll
        for (int rd = 0; rd < 2; ++rd)
            LDS_GL16(src + goff[r * 2 + rd] + kt * 64,
                     lds + p * 16384 + doff[r * 2 + rd]);
    };

    // ---- affine fragment-read base pointers (byte addressed)
    const char* ldsc = (const char*)lds;
    int swz = lr & 7;
    const char* baseA[2], *baseB[2];
    baseA[0] = ldsc + (wm * 128 + lr) * 128 + ((g ^ swz) << 4);
    baseA[1] = ldsc + (wm * 128 + lr) * 128 + (((4 + g) ^ swz) << 4);
    baseB[0] = ldsc + 65536 + (wn * 64 + lr) * 128 + ((g ^ swz) << 4);
    baseB[1] = ldsc + 65536 + (wn * 64 + lr) * 128 + (((4 + g) ^ swz) << 4);

    f32x4 acc[8][4] = {};
    f16x8 a[4][2], b0[2][2], b1[2][2];

    auto loadA = [&](int bufB, int qm) {       // bufB: 0 or 32768 (literal)
        #pragma unroll
        for (int mf = 0; mf < 4; ++mf)
            #pragma unroll
            for (int kk = 0; kk < 2; ++kk)
                a[mf][kk] = *(const f16x8*)(baseA[kk] + bufB + qm * 8192 + mf * 2048);
    };
    auto loadB = [&](f16x8 (&d)[2][2], int bufB, int qn) {
        #pragma unroll
        for (int nf = 0; nf < 2; ++nf)
            #pragma unroll
            for (int kk = 0; kk < 2; ++kk)
                d[nf][kk] = *(const f16x8*)(baseB[kk] + bufB + qn * 4096 + nf * 2048);
    };
    auto mma = [&](f16x8 (&bb)[2][2], int qm, int qn) {
        __builtin_amdgcn_s_setprio(1);
        #pragma unroll
        for (int kk = 0; kk < 2; ++kk)
            #pragma unroll
            for (int mf = 0; mf < 4; ++mf)
                #pragma unroll
                for (int nf = 0; nf < 2; ++nf)
                    acc[qm * 4 + mf][qn * 2 + nf] = __builtin_amdgcn_mfma_f32_16x16x32_f16(
                        a[mf][kk], bb[nf][kk], acc[qm * 4 + mf][qn * 2 + nf], 0, 0, 0);
        __builtin_amdgcn_s_setprio(0);
    };

    int NT = Kd >> 6, NI = NT >> 1;

    // prologue: tile0 all 4 regions -> buf0; tile1 A0,B0,B1 -> buf1
    stage(0, 0, 0); stage(0, 0, 1); stage(0, 0, 2); stage(0, 0, 3);
    stage(1, 1, 0); stage(1, 1, 1); stage(1, 1, 2);
    VMCNT(6); BAR();                 // tile0 landed; 6 in flight

    for (int it = 0; it < NI - 1; ++it) {
        int t0 = it * 2;
        // p1: q(0,0) tile t0 (buf0)
        loadA(0, 0); loadB(b0, 0, 0);
        stage(t0 + 1, 1, 3);
        BAR(); mma(b0, 0, 0); BAR();
        // p2: q(0,1)
        loadB(b1, 0, 1);
        stage(t0 + 2, 0, 0);
        BAR(); mma(b1, 0, 1); BAR();
        // p3: q(1,1)
        loadA(0, 1);
        stage(t0 + 2, 0, 1);
        BAR(); mma(b1, 1, 1); BAR();
        // p4: q(1,0)  (b0 held from p1)
        stage(t0 + 2, 0, 2);
        VMCNT(6);                    // tile t0+1 fully landed
        BAR(); mma(b0, 1, 0); BAR();
        // p5: q(0,0) tile t0+1 (buf1)
        loadA(32768, 0); loadB(b0, 32768, 0);
        stage(t0 + 2, 0, 3);
        BAR(); mma(b0, 0, 0); BAR();
        // p6
        loadB(b1, 32768, 1);
        stage(t0 + 3, 1, 0);
        BAR(); mma(b1, 0, 1); BAR();
        // p7
        loadA(32768, 1);
        stage(t0 + 3, 1, 1);
        BAR(); mma(b1, 1, 1); BAR();
        // p8
        stage(t0 + 3, 1, 2);
        VMCNT(6);                    // tile t0+2 fully landed
        BAR(); mma(b0, 1, 0); BAR();
    }
    {   // final iteration (tiles NT-2, NT-1): only p1 stages
        loadA(0, 0); loadB(b0, 0, 0);
        stage(NT - 1, 1, 3);
        BAR(); mma(b0, 0, 0); BAR();
        loadB(b1, 0, 1);
        BAR(); mma(b1, 0, 1); BAR();
        loadA(0, 1);
        BAR(); mma(b1, 1, 1); BAR();
        VMCNT(0);                    // tile NT-1 fully landed
        BAR(); mma(b0, 1, 0); BAR();
        loadA(32768, 0); loadB(b0, 32768, 0);
        BAR(); mma(b0, 0, 0); BAR();
        loadB(b1, 32768, 1);
        BAR(); mma(b1, 0, 1); BAR();
        loadA(32768, 1);
        BAR(); mma(b1, 1, 1); BAR();
        BAR(); mma(b0, 1, 0);
    }

    #pragma unroll
    for (int i = 0; i < 8; ++i) {
        #pragma unroll
        for (int j = 0; j < 4; ++j) {
            #pragma unroll
            for (int reg = 0; reg < 4; ++reg) {
                int row = m0 + wm * 128 + i * 16 + g * 4 + reg;
                int col = n0 + wn * 64 + j * 16 + lr;
                long idx = (long)row * N + col;
                float v = acc[i][j][reg];
                if (EPI == 0) Ch[idx] = (f16)v;
                else          Cf[idx] = v + resid[idx];
            }
        }
    }
}

// ---------------- Attention: one block per (b,l,k,h) -----------------------
__global__ __launch_bounds__(256, 2) void attn_kern(
        const f16* __restrict__ Q,    // [8192, 2048]
        const f16* __restrict__ KV,   // [8192, 4096]  (k | v)
        const float* __restrict__ mask,      // [64*128]
        const float* __restrict__ bias,      // [32*16]
        float* __restrict__ attn_out,        // (B,L,K,H,R,M) f32
        f16* __restrict__ pv_out) {          // [8192, 2048]
    __shared__ f16 Vs[128 * 128];
    __shared__ f16 P[64 * 136];
    int blk = blockIdx.x;
    int h  = blk & 15;
    int bk = blk >> 4;
    int bl = bk >> 1;
    int tid = threadIdx.x, lane = tid & 63, w = tid >> 6;
    int r0 = w << 4;
    int lr = lane & 15, g = lane >> 4;
    long qbase  = (long)bk * 64 * 2048;
    long kvbase = (long)bl * 128 * 4096;
    const f16* vsrc = KV + kvbase + 2048 + h * 128;
    {
        int idx = tid;
        #pragma unroll
        for (int rnd = 0; rnd < 8; ++rnd) {
            int vrow = idx >> 4, c = idx & 15;
            LDS_GL16(vsrc + (long)vrow * 4096 + c * 8, Vs + idx * 8);
            idx += 256;
        }
    }
    f16x8 aq[4];
    const f16* qrow = Q + qbase + (long)(r0 + lr) * 2048 + h * 128 + g * 8;
    #pragma unroll
    for (int t4 = 0; t4 < 4; ++t4) aq[t4] = *(const f16x8*)(qrow + t4 * 32);
    f32x4 s[8] = {};
    const f16* kbase = KV + kvbase + h * 128 + g * 8;
    #pragma unroll
    for (int j = 0; j < 8; ++j) {
        #pragma unroll
        for (int t4 = 0; t4 < 4; ++t4) {
            f16x8 bkf = *(const f16x8*)(kbase + (long)(j * 16 + lr) * 4096 + t4 * 32);
            s[j] = __builtin_amdgcn_mfma_f32_16x16x32_f16(aq[t4], bkf, s[j], 0, 0, 0);
        }
    }
    float madd[8];
    #pragma unroll
    for (int j = 0; j < 8; ++j)
        madd[j] = (1.0f - mask[(long)bl * 128 + j * 16 + lr]) * -10000.0f;
    #pragma unroll
    for (int reg = 0; reg < 4; ++reg) {
        int r = r0 + g * 4 + reg;
        float mx = -3.0e38f;
        #pragma unroll
        for (int j = 0; j < 8; ++j) {
            int m = j * 16 + lr;
            int rel = m - r;
            int bkt = (rel < -15 ? -15 : (rel > 16 ? 16 : rel)) + 15;
            float v = s[j][reg] + bias[bkt * 16 + h] + madd[j];
            s[j][reg] = v;
            mx = fmaxf(mx, v);
        }
        #pragma unroll
        for (int d = 1; d < 16; d <<= 1) mx = fmaxf(mx, __shfl_xor(mx, d, 64));
        float sum = 0.0f;
        #pragma unroll
        for (int j = 0; j < 8; ++j) {
            float e = __expf(s[j][reg] - mx);
            s[j][reg] = e;
            sum += e;
        }
        #pragma unroll
        for (int d = 1; d < 16; d <<= 1) sum += __shfl_xor(sum, d, 64);
        float inv = 1.0f / sum;
        #pragma unroll
        for (int j = 0; j < 8; ++j) s[j][reg] *= inv;
    }
    long abase = (long)blk * 64 * 128;
    #pragma unroll
    for (int reg = 0; reg < 4; ++reg) {
        int r = r0 + g * 4 + reg;
        #pragma unroll
        for (int j = 0; j < 8; ++j) {
            attn_out[abase + (long)r * 128 + j * 16 + lr] = s[j][reg];
            P[r * 136 + j * 16 + lr] = (f16)s[j][reg];
        }
    }
    __syncthreads();
    f16x8 pa[4];
    #pragma unroll
    for (int t4 = 0; t4 < 4; ++t4)
        pa[t4] = *(const f16x8*)(P + (r0 + lr) * 136 + t4 * 32 + g * 8);
    f32x4 o[8] = {};
    #pragma unroll
    for (int dj = 0; dj < 8; ++dj) {
        #pragma unroll
        for (int t4 = 0; t4 < 4; ++t4) {
            f16x8 bv;
            #pragma unroll
            for (int rg = 0; rg < 8; ++rg)
                bv[rg] = Vs[(t4 * 32 + g * 8 + rg) * 128 + dj * 16 + lr];
            o[dj] = __builtin_amdgcn_mfma_f32_16x16x32_f16(pa[t4], bv, o[dj], 0, 0, 0);
        }
    }
    f16* ob = pv_out + qbase + h * 128;
    #pragma unroll
    for (int dj = 0; dj < 8; ++dj)
        #pragma unroll
        for (int reg = 0; reg < 4; ++reg)
            ob[(long)(r0 + g * 4 + reg) * 2048 + dj * 16 + lr] = (f16)o[dj][reg];
}

extern "C" void kernel_launch(void* const* d_in, const int* in_sizes, int n_in,
                              void* d_out, int out_size, void* d_ws, size_t ws_size,
                              hipStream_t stream) {
    const float* x     = (const float*)d_in[0];
    const float* hid   = (const float*)d_in[1];
    const float* mask  = (const float*)d_in[2];
    const float* lnsc  = (const float*)d_in[3];
    const float* q_w   = (const float*)d_in[4];
    const float* kv_w  = (const float*)d_in[5];
    const float* out_w = (const float*)d_in[6];
    const float* bias  = (const float*)d_in[7];
    float* out0 = (float*)d_out;             // (B,L,K,R,Dm) = 16,777,216 f32
    float* attn = out0 + 16777216;           // (B,L,K,H,R,M) = 16,777,216 f32

    // Scratch aliased into dead d_out regions (lifetimes stream-ordered):
    f16* kv_h  = (f16*)out0;                 // dead until final GEMM
    f16* xn_h  = (f16*)attn;                 // dead until attn_kern writes attn
    f16* hid_h = (f16*)(attn + 8388608);
    char* ws = (char*)d_ws;
    f16* q_h    = (f16*)(ws);                 // 32 MiB
    f16* ao_h   = (f16*)(ws + 33554432L);     // 32 MiB
    f16* qw_h   = (f16*)(ws + 67108864L);     //  8 MiB
    f16* kvw_h  = (f16*)(ws + 75497472L);     // 16 MiB
    f16* outw_h = (f16*)(ws + 92274688L);     //  8 MiB -> 96 MiB total

    conv4_kern<<<16384, 256, 0, stream>>>(q_w, qw_h, kv_w, kvw_h,
                                          out_w, outw_h, hid, hid_h);
    rmsnorm_kern<<<8192, 256, 0, stream>>>(x, lnsc, xn_h);
    gemm256<0><<<256, 512, 0, stream>>>(xn_h, qw_h, q_h, nullptr, nullptr,
                                        8192, 2048, 2048);
    gemm256<0><<<512, 512, 0, stream>>>(hid_h, kvw_h, kv_h, nullptr, nullptr,
                                        8192, 4096, 2048);
    attn_kern<<<2048, 256, 0, stream>>>(q_h, kv_h, mask, bias, attn, ao_h);
    gemm256<1><<<256, 512, 0, stream>>>(ao_h, outw_h, nullptr, out0, x,
                                        8192, 2048, 2048);
}

// Round 7
// 375.854 us; speedup vs baseline: 1.2827x; 1.0250x over previous
//
#include <hip/hip_runtime.h>

typedef _Float16 f16;
typedef _Float16 f16x8 __attribute__((ext_vector_type(8)));
typedef float f32x4 __attribute__((ext_vector_type(4)));

#define LDS_GL16(g, l) __builtin_amdgcn_global_load_lds( \
    (const __attribute__((address_space(1))) void*)(g),  \
    (__attribute__((address_space(3))) void*)(l), 16, 0, 0)
#define VMCNT(N) asm volatile("s_waitcnt vmcnt(" #N ")" ::: "memory")
#define BAR() __builtin_amdgcn_s_barrier()

// ------- segmented f32 -> f16 convert: 4 buffers in one launch -------------
__global__ __launch_bounds__(256) void conv4_kern(
        const float* __restrict__ s0, f16* __restrict__ d0,
        const float* __restrict__ s1, f16* __restrict__ d1,
        const float* __restrict__ s2, f16* __restrict__ d2,
        const float* __restrict__ s3, f16* __restrict__ d3) {
    int b = blockIdx.x;
    const float* in; f16* out; long base;
    if (b < 2048)       { in = s0; out = d0; base = (long)b * 2048; }
    else if (b < 6144)  { in = s1; out = d1; base = (long)(b - 2048) * 2048; }
    else if (b < 8192)  { in = s2; out = d2; base = (long)(b - 6144) * 2048; }
    else                { in = s3; out = d3; base = (long)(b - 8192) * 2048; }
    long o = base + threadIdx.x * 8;
    float4 a = *(const float4*)(in + o);
    float4 c = *(const float4*)(in + o + 4);
    f16x8 v = { (f16)a.x,(f16)a.y,(f16)a.z,(f16)a.w,
                (f16)c.x,(f16)c.y,(f16)c.z,(f16)c.w };
    *(f16x8*)(out + o) = v;
}

// ---------------- RMSNorm: one block per row of 2048 (8192 rows) -----------
__global__ __launch_bounds__(256) void rmsnorm_kern(const float* __restrict__ x,
                                                    const float* __restrict__ scale,
                                                    f16* __restrict__ out) {
    long base = (long)blockIdx.x * 2048 + threadIdx.x * 8;
    float4 a = *(const float4*)(x + base);
    float4 b = *(const float4*)(x + base + 4);
    float ss = a.x*a.x + a.y*a.y + a.z*a.z + a.w*a.w
             + b.x*b.x + b.y*b.y + b.z*b.z + b.w*b.w;
    #pragma unroll
    for (int d = 1; d < 64; d <<= 1) ss += __shfl_xor(ss, d, 64);
    __shared__ float red[4];
    if ((threadIdx.x & 63) == 0) red[threadIdx.x >> 6] = ss;
    __syncthreads();
    ss = red[0] + red[1] + red[2] + red[3];
    float inv = 1.0f / (sqrtf(ss * (1.0f / 2048.0f)) + 1e-8f);
    int c = threadIdx.x * 8;
    float4 s1 = *(const float4*)(scale + c);
    float4 s2 = *(const float4*)(scale + c + 4);
    f16x8 v = { (f16)(a.x*inv*s1.x),(f16)(a.y*inv*s1.y),(f16)(a.z*inv*s1.z),(f16)(a.w*inv*s1.w),
                (f16)(b.x*inv*s2.x),(f16)(b.y*inv*s2.y),(f16)(b.z*inv*s2.z),(f16)(b.w*inv*s2.w) };
    *(f16x8*)(out + base) = v;
}

// ---------------- GEMM 256x256 body, BK=64, 8 waves, 8-phase pipelined -----
// C[M,N] = A[M,K] * B[N,K]^T.  EPI=0: f16 out. EPI=1: f32 out + resid.
// Epilogue: LDS bounce -> fully coalesced dwordx4 stores.
template<int EPI>
__device__ __forceinline__ void gemm256_body(
        const f16* __restrict__ A, const f16* __restrict__ B,
        f16* __restrict__ Ch, float* __restrict__ Cf,
        const float* __restrict__ resid, int N, int Kd, int m0, int n0) {
    alignas(16) __shared__ f16 lds[65536];
    int tid = threadIdx.x, lane = tid & 63;
    int wid = tid >> 6, wm = wid >> 2, wn = wid & 3;
    int lr = lane & 15, g = lane >> 4;
    int iL = tid >> 3, cb = tid & 7;

    long goff[8]; int doff[8];
    #pragma unroll
    for (int rd = 0; rd < 2; ++rd) {
        int rA0 = iL + rd * 128;
        goff[0 + rd] = (long)(m0 + rA0) * Kd + ((cb ^ (rA0 & 7)) << 3);
        doff[0 + rd] = rA0 * 64 + cb * 8;
        int rB0 = (iL & 31) + ((iL >> 5) + rd * 2) * 64;
        goff[2 + rd] = (long)(n0 + rB0) * Kd + ((cb ^ (rB0 & 7)) << 3);
        doff[2 + rd] = 32768 + rB0 * 64 + cb * 8;
        int rB1 = rB0 + 32;
        goff[4 + rd] = (long)(n0 + rB1) * Kd + ((cb ^ (rB1 & 7)) << 3);
        doff[4 + rd] = 32768 + rB1 * 64 + cb * 8;
        int rA1 = rA0 + 64;
        goff[6 + rd] = (long)(m0 + rA1) * Kd + ((cb ^ (rA1 & 7)) << 3);
        doff[6 + rd] = rA1 * 64 + cb * 8;
    }
    auto stage = [&](int kt, int p, int r) {
        const f16* src = (r == 0 || r == 3) ? A : B;
        #pragma unroll
        for (int rd = 0; rd < 2; ++rd)
            LDS_GL16(src + goff[r * 2 + rd] + kt * 64,
                     lds + p * 16384 + doff[r * 2 + rd]);
    };

    const char* ldsc = (const char*)lds;
    int swz = lr & 7;
    const char* baseA[2], *baseB[2];
    baseA[0] = ldsc + (wm * 128 + lr) * 128 + ((g ^ swz) << 4);
    baseA[1] = ldsc + (wm * 128 + lr) * 128 + (((4 + g) ^ swz) << 4);
    baseB[0] = ldsc + 65536 + (wn * 64 + lr) * 128 + ((g ^ swz) << 4);
    baseB[1] = ldsc + 65536 + (wn * 64 + lr) * 128 + (((4 + g) ^ swz) << 4);

    f32x4 acc[8][4] = {};
    f16x8 a[4][2], b0[2][2], b1[2][2];

    auto loadA = [&](int bufB, int qm) {
        #pragma unroll
        for (int mf = 0; mf < 4; ++mf)
            #pragma unroll
            for (int kk = 0; kk < 2; ++kk)
                a[mf][kk] = *(const f16x8*)(baseA[kk] + bufB + qm * 8192 + mf * 2048);
    };
    auto loadB = [&](f16x8 (&d)[2][2], int bufB, int qn) {
        #pragma unroll
        for (int nf = 0; nf < 2; ++nf)
            #pragma unroll
            for (int kk = 0; kk < 2; ++kk)
                d[nf][kk] = *(const f16x8*)(baseB[kk] + bufB + qn * 4096 + nf * 2048);
    };
    auto mma = [&](f16x8 (&bb)[2][2], int qm, int qn) {
        __builtin_amdgcn_s_setprio(1);
        #pragma unroll
        for (int kk = 0; kk < 2; ++kk)
            #pragma unroll
            for (int mf = 0; mf < 4; ++mf)
                #pragma unroll
                for (int nf = 0; nf < 2; ++nf)
                    acc[qm * 4 + mf][qn * 2 + nf] = __builtin_amdgcn_mfma_f32_16x16x32_f16(
                        a[mf][kk], bb[nf][kk], acc[qm * 4 + mf][qn * 2 + nf], 0, 0, 0);
        __builtin_amdgcn_s_setprio(0);
    };

    int NT = Kd >> 6, NI = NT >> 1;

    stage(0, 0, 0); stage(0, 0, 1); stage(0, 0, 2); stage(0, 0, 3);
    stage(1, 1, 0); stage(1, 1, 1); stage(1, 1, 2);
    VMCNT(6); BAR();                 // tile0 landed; 6 in flight

    for (int it = 0; it < NI - 1; ++it) {
        int t0 = it * 2;
        loadA(0, 0); loadB(b0, 0, 0);
        stage(t0 + 1, 1, 3);
        BAR(); mma(b0, 0, 0); BAR();
        loadB(b1, 0, 1);
        stage(t0 + 2, 0, 0);
        BAR(); mma(b1, 0, 1); BAR();
        loadA(0, 1);
        stage(t0 + 2, 0, 1);
        BAR(); mma(b1, 1, 1); BAR();
        stage(t0 + 2, 0, 2);
        VMCNT(6);                    // tile t0+1 fully landed
        BAR(); mma(b0, 1, 0); BAR();
        loadA(32768, 0); loadB(b0, 32768, 0);
        stage(t0 + 2, 0, 3);
        BAR(); mma(b0, 0, 0); BAR();
        loadB(b1, 32768, 1);
        stage(t0 + 3, 1, 0);
        BAR(); mma(b1, 0, 1); BAR();
        loadA(32768, 1);
        stage(t0 + 3, 1, 1);
        BAR(); mma(b1, 1, 1); BAR();
        stage(t0 + 3, 1, 2);
        VMCNT(6);                    // tile t0+2 fully landed
        BAR(); mma(b0, 1, 0); BAR();
    }
    {   // final iteration (tiles NT-2, NT-1): only p1 stages
        loadA(0, 0); loadB(b0, 0, 0);
        stage(NT - 1, 1, 3);
        BAR(); mma(b0, 0, 0); BAR();
        loadB(b1, 0, 1);
        BAR(); mma(b1, 0, 1); BAR();
        loadA(0, 1);
        BAR(); mma(b1, 1, 1); BAR();
        VMCNT(0);                    // tile NT-1 fully landed
        BAR(); mma(b0, 1, 0); BAR();
        loadA(32768, 0); loadB(b0, 32768, 0);
        BAR(); mma(b0, 0, 0); BAR();
        loadB(b1, 32768, 1);
        BAR(); mma(b1, 0, 1); BAR();
        loadA(32768, 1);
        BAR(); mma(b1, 1, 1); BAR();
        BAR(); mma(b0, 1, 0);
    }

    // ---- epilogue: LDS bounce -> coalesced stores ----
    __syncthreads();                 // K-loop LDS dead
    if (EPI == 0) {
        #pragma unroll
        for (int i = 0; i < 8; ++i)
            #pragma unroll
            for (int j = 0; j < 4; ++j)
                #pragma unroll
                for (int reg = 0; reg < 4; ++reg)
                    lds[(wm * 128 + i * 16 + g * 4 + reg) * 256 + wn * 64 + j * 16 + lr] =
                        (f16)acc[i][j][reg];
        __syncthreads();
        #pragma unroll
        for (int k = 0; k < 16; ++k) {
            int e = k * 4096 + tid * 8;          // f16 elem in [256][256]
            int row = e >> 8, col = e & 255;
            *(f16x8*)(Ch + (long)(m0 + row) * N + n0 + col) = *(const f16x8*)(lds + e);
        }
    } else {
        float* Ct = (float*)lds;                 // [128][256] f32 per pass
        #pragma unroll
        for (int h = 0; h < 2; ++h) {
            if (h) __syncthreads();
            if (wm == h) {
                #pragma unroll
                for (int i = 0; i < 8; ++i)
                    #pragma unroll
                    for (int j = 0; j < 4; ++j)
                        #pragma unroll
                        for (int reg = 0; reg < 4; ++reg)
                            Ct[(i * 16 + g * 4 + reg) * 256 + wn * 64 + j * 16 + lr] =
                                acc[i][j][reg];
            }
            __syncthreads();
            #pragma unroll
            for (int k = 0; k < 8; ++k) {
                int e = k * 4096 + tid * 8;      // f32 elem in [128][256]
                int row = e >> 8, col = e & 255;
                long gi = (long)(m0 + h * 128 + row) * N + n0 + col;
                float4 c0 = *(const float4*)(Ct + e);
                float4 c1 = *(const float4*)(Ct + e + 4);
                float4 r0 = *(const float4*)(resid + gi);
                float4 r1 = *(const float4*)(resid + gi + 4);
                c0.x += r0.x; c0.y += r0.y; c0.z += r0.z; c0.w += r0.w;
                c1.x += r1.x; c1.y += r1.y; c1.z += r1.z; c1.w += r1.w;
                *(float4*)(Cf + gi) = c0;
                *(float4*)(Cf + gi + 4) = c1;
            }
        }
    }
}

// ---- merged q+kv projection: grid 768 (q: 256 blocks, kv: 512 blocks) -----
__global__ __launch_bounds__(512, 2) void gemm_qkv(
        const f16* __restrict__ Aq, const f16* __restrict__ Bq, f16* __restrict__ Cq,
        const f16* __restrict__ Akv, const f16* __restrict__ Bkv, f16* __restrict__ Ckv) {
    int fid = (blockIdx.x & 7) * 96 + (blockIdx.x >> 3);   // XCD swizzle, 768 = 8*96
    const f16 *A, *B; f16* C; int N, lf, sh;
    if (fid < 256) { A = Aq;  B = Bq;  C = Cq;  N = 2048; lf = fid;       sh = 3; }
    else           { A = Akv; B = Bkv; C = Ckv; N = 4096; lf = fid - 256; sh = 4; }
    int by = lf >> sh, bx = lf & ((1 << sh) - 1);
    gemm256_body<0>(A, B, C, nullptr, nullptr, N, 2048, by << 8, bx << 8);
}

// ---- output projection + residual: grid 256 ----
__global__ __launch_bounds__(512, 2) void gemm_out(
        const f16* __restrict__ A, const f16* __restrict__ B,
        float* __restrict__ Cf, const float* __restrict__ resid) {
    int fid = (blockIdx.x & 7) * 32 + (blockIdx.x >> 3);   // 256 = 8*32
    int by = fid >> 3, bx = fid & 7;
    gemm256_body<1>(A, B, nullptr, Cf, resid, 2048, 2048, by << 8, bx << 8);
}

// ---------------- Attention: one block per (b,l,k,h) -----------------------
__global__ __launch_bounds__(256, 2) void attn_kern(
        const f16* __restrict__ Q,    // [8192, 2048]
        const f16* __restrict__ KV,   // [8192, 4096]  (k | v)
        const float* __restrict__ mask,      // [64*128]
        const float* __restrict__ bias,      // [32*16]
        float* __restrict__ attn_out,        // (B,L,K,H,R,M) f32
        f16* __restrict__ pv_out) {          // [8192, 2048]
    __shared__ f16 Vs[128 * 128];
    __shared__ f16 P[64 * 136];
    int blk = blockIdx.x;
    int h  = blk & 15;
    int bk = blk >> 4;
    int bl = bk >> 1;
    int tid = threadIdx.x, lane = tid & 63, w = tid >> 6;
    int r0 = w << 4;
    int lr = lane & 15, g = lane >> 4;
    long qbase  = (long)bk * 64 * 2048;
    long kvbase = (long)bl * 128 * 4096;
    const f16* vsrc = KV + kvbase + 2048 + h * 128;
    {
        int idx = tid;
        #pragma unroll
        for (int rnd = 0; rnd < 8; ++rnd) {
            int vrow = idx >> 4, c = idx & 15;
            LDS_GL16(vsrc + (long)vrow * 4096 + c * 8, Vs + idx * 8);
            idx += 256;
        }
    }
    f16x8 aq[4];
    const f16* qrow = Q + qbase + (long)(r0 + lr) * 2048 + h * 128 + g * 8;
    #pragma unroll
    for (int t4 = 0; t4 < 4; ++t4) aq[t4] = *(const f16x8*)(qrow + t4 * 32);
    f32x4 s[8] = {};
    const f16* kbase = KV + kvbase + h * 128 + g * 8;
    #pragma unroll
    for (int j = 0; j < 8; ++j) {
        #pragma unroll
        for (int t4 = 0; t4 < 4; ++t4) {
            f16x8 bkf = *(const f16x8*)(kbase + (long)(j * 16 + lr) * 4096 + t4 * 32);
            s[j] = __builtin_amdgcn_mfma_f32_16x16x32_f16(aq[t4], bkf, s[j], 0, 0, 0);
        }
    }
    float madd[8];
    #pragma unroll
    for (int j = 0; j < 8; ++j)
        madd[j] = (1.0f - mask[(long)bl * 128 + j * 16 + lr]) * -10000.0f;
    #pragma unroll
    for (int reg = 0; reg < 4; ++reg) {
        int r = r0 + g * 4 + reg;
        float mx = -3.0e38f;
        #pragma unroll
        for (int j = 0; j < 8; ++j) {
            int m = j * 16 + lr;
            int rel = m - r;
            int bkt = (rel < -15 ? -15 : (rel > 16 ? 16 : rel)) + 15;
            float v = s[j][reg] + bias[bkt * 16 + h] + madd[j];
            s[j][reg] = v;
            mx = fmaxf(mx, v);
        }
        #pragma unroll
        for (int d = 1; d < 16; d <<= 1) mx = fmaxf(mx, __shfl_xor(mx, d, 64));
        float sum = 0.0f;
        #pragma unroll
        for (int j = 0; j < 8; ++j) {
            float e = __expf(s[j][reg] - mx);
            s[j][reg] = e;
            sum += e;
        }
        #pragma unroll
        for (int d = 1; d < 16; d <<= 1) sum += __shfl_xor(sum, d, 64);
        float inv = 1.0f / sum;
        #pragma unroll
        for (int j = 0; j < 8; ++j) s[j][reg] *= inv;
    }
    long abase = (long)blk * 64 * 128;
    #pragma unroll
    for (int reg = 0; reg < 4; ++reg) {
        int r = r0 + g * 4 + reg;
        #pragma unroll
        for (int j = 0; j < 8; ++j) {
            attn_out[abase + (long)r * 128 + j * 16 + lr] = s[j][reg];
            P[r * 136 + j * 16 + lr] = (f16)s[j][reg];
        }
    }
    __syncthreads();   // V staged (vmcnt drained) + P visible
    f16x8 pa[4];
    #pragma unroll
    for (int t4 = 0; t4 < 4; ++t4)
        pa[t4] = *(const f16x8*)(P + (r0 + lr) * 136 + t4 * 32 + g * 8);
    f32x4 o[8] = {};
    #pragma unroll
    for (int dj = 0; dj < 8; ++dj) {
        #pragma unroll
        for (int t4 = 0; t4 < 4; ++t4) {
            f16x8 bv;
            #pragma unroll
            for (int rg = 0; rg < 8; ++rg)
                bv[rg] = Vs[(t4 * 32 + g * 8 + rg) * 128 + dj * 16 + lr];
            o[dj] = __builtin_amdgcn_mfma_f32_16x16x32_f16(pa[t4], bv, o[dj], 0, 0, 0);
        }
    }
    // bounce o through Vs (dead now) -> coalesced f16x8 stores
    __syncthreads();   // all waves done reading Vs
    #pragma unroll
    for (int dj = 0; dj < 8; ++dj)
        #pragma unroll
        for (int reg = 0; reg < 4; ++reg)
            Vs[(r0 + g * 4 + reg) * 128 + dj * 16 + lr] = (f16)o[dj][reg];
    __syncthreads();
    f16* ob = pv_out + qbase + h * 128;
    #pragma unroll
    for (int k = 0; k < 4; ++k) {
        int e = k * 2048 + tid * 8;              // f16 elem in [64][128]
        int row = e >> 7, col = e & 127;
        *(f16x8*)(ob + (long)row * 2048 + col) = *(const f16x8*)(Vs + e);
    }
}

extern "C" void kernel_launch(void* const* d_in, const int* in_sizes, int n_in,
                              void* d_out, int out_size, void* d_ws, size_t ws_size,
                              hipStream_t stream) {
    const float* x     = (const float*)d_in[0];
    const float* hid   = (const float*)d_in[1];
    const float* mask  = (const float*)d_in[2];
    const float* lnsc  = (const float*)d_in[3];
    const float* q_w   = (const float*)d_in[4];
    const float* kv_w  = (const float*)d_in[5];
    const float* out_w = (const float*)d_in[6];
    const float* bias  = (const float*)d_in[7];
    float* out0 = (float*)d_out;             // (B,L,K,R,Dm) = 16,777,216 f32
    float* attn = out0 + 16777216;           // (B,L,K,H,R,M) = 16,777,216 f32

    // Scratch aliased into dead d_out regions (lifetimes stream-ordered):
    f16* kv_h  = (f16*)out0;                 // dead until final GEMM
    f16* xn_h  = (f16*)attn;                 // dead until attn_kern writes attn
    f16* hid_h = (f16*)(attn + 8388608);
    char* ws = (char*)d_ws;
    f16* q_h    = (f16*)(ws);                 // 32 MiB
    f16* ao_h   = (f16*)(ws + 33554432L);     // 32 MiB
    f16* qw_h   = (f16*)(ws + 67108864L);     //  8 MiB
    f16* kvw_h  = (f16*)(ws + 75497472L);     // 16 MiB
    f16* outw_h = (f16*)(ws + 92274688L);     //  8 MiB -> 96 MiB total

    conv4_kern<<<16384, 256, 0, stream>>>(q_w, qw_h, kv_w, kvw_h,
                                          out_w, outw_h, hid, hid_h);
    rmsnorm_kern<<<8192, 256, 0, stream>>>(x, lnsc, xn_h);
    gemm_qkv<<<768, 512, 0, stream>>>(xn_h, qw_h, q_h, hid_h, kvw_h, kv_h);
    attn_kern<<<2048, 256, 0, stream>>>(q_h, kv_h, mask, bias, attn, ao_h);
    gemm_out<<<256, 512, 0, stream>>>(ao_h, outw_h, out0, x);
}

// Round 8
// 370.063 us; speedup vs baseline: 1.3027x; 1.0156x over previous
//
#include <hip/hip_runtime.h>

typedef _Float16 f16;
typedef _Float16 f16x8 __attribute__((ext_vector_type(8)));
typedef float f32x4 __attribute__((ext_vector_type(4)));

#define LDS_GL16(g, l) __builtin_amdgcn_global_load_lds( \
    (const __attribute__((address_space(1))) void*)(g),  \
    (__attribute__((address_space(3))) void*)(l), 16, 0, 0)
#define VMCNT(N) asm volatile("s_waitcnt vmcnt(" #N ")" ::: "memory")
#define BAR() __builtin_amdgcn_s_barrier()

// ---- fused prep: f32->f16 converts (4 bufs) + RMSNorm, one launch ---------
// blocks: qw 2048 | kvw 4096 | outw 2048 | hid 8192 | rms 8192  (24576)
__global__ __launch_bounds__(256) void prep_kern(
        const float* __restrict__ qw,   f16* __restrict__ qwh,
        const float* __restrict__ kvw,  f16* __restrict__ kvwh,
        const float* __restrict__ outw, f16* __restrict__ outwh,
        const float* __restrict__ hid,  f16* __restrict__ hidh,
        const float* __restrict__ x, const float* __restrict__ lnsc,
        f16* __restrict__ xnh) {
    int b = blockIdx.x;
    if (b >= 16384) {   // RMSNorm row
        long base = (long)(b - 16384) * 2048 + threadIdx.x * 8;
        float4 a = *(const float4*)(x + base);
        float4 v = *(const float4*)(x + base + 4);
        float ss = a.x*a.x + a.y*a.y + a.z*a.z + a.w*a.w
                 + v.x*v.x + v.y*v.y + v.z*v.z + v.w*v.w;
        #pragma unroll
        for (int d = 1; d < 64; d <<= 1) ss += __shfl_xor(ss, d, 64);
        __shared__ float red[4];
        if ((threadIdx.x & 63) == 0) red[threadIdx.x >> 6] = ss;
        __syncthreads();
        ss = red[0] + red[1] + red[2] + red[3];
        float inv = 1.0f / (sqrtf(ss * (1.0f / 2048.0f)) + 1e-8f);
        int c = threadIdx.x * 8;
        float4 s1 = *(const float4*)(lnsc + c);
        float4 s2 = *(const float4*)(lnsc + c + 4);
        f16x8 o = { (f16)(a.x*inv*s1.x),(f16)(a.y*inv*s1.y),(f16)(a.z*inv*s1.z),(f16)(a.w*inv*s1.w),
                    (f16)(v.x*inv*s2.x),(f16)(v.y*inv*s2.y),(f16)(v.z*inv*s2.z),(f16)(v.w*inv*s2.w) };
        *(f16x8*)(xnh + base) = o;
        return;
    }
    const float* in; f16* out; long base;
    if (b < 2048)       { in = qw;   out = qwh;   base = (long)b * 2048; }
    else if (b < 6144)  { in = kvw;  out = kvwh;  base = (long)(b - 2048) * 2048; }
    else if (b < 8192)  { in = outw; out = outwh; base = (long)(b - 6144) * 2048; }
    else                { in = hid;  out = hidh;  base = (long)(b - 8192) * 2048; }
    long o = base + threadIdx.x * 8;
    float4 a = *(const float4*)(in + o);
    float4 c = *(const float4*)(in + o + 4);
    f16x8 v = { (f16)a.x,(f16)a.y,(f16)a.z,(f16)a.w,
                (f16)c.x,(f16)c.y,(f16)c.z,(f16)c.w };
    *(f16x8*)(out + o) = v;
}

// ---------------- GEMM 256x256 body, BK=64, 8 waves, 8-phase pipelined -----
// C[M,N] = A[M,K] * B[N,K]^T.  EPI=0: f16 out. EPI=1: f32 out + resid.
// Epilogue: LDS bounce with XOR de-conflict -> coalesced dwordx4 stores.
template<int EPI>
__device__ __forceinline__ void gemm256_body(
        const f16* __restrict__ A, const f16* __restrict__ B,
        f16* __restrict__ Ch, float* __restrict__ Cf,
        const float* __restrict__ resid, int N, int Kd, int m0, int n0) {
    alignas(16) __shared__ f16 lds[65536];
    int tid = threadIdx.x, lane = tid & 63;
    int wid = tid >> 6, wm = wid >> 2, wn = wid & 3;
    int lr = lane & 15, g = lane >> 4;
    int iL = tid >> 3, cb = tid & 7;

    long goff[8]; int doff[8];
    #pragma unroll
    for (int rd = 0; rd < 2; ++rd) {
        int rA0 = iL + rd * 128;
        goff[0 + rd] = (long)(m0 + rA0) * Kd + ((cb ^ (rA0 & 7)) << 3);
        doff[0 + rd] = rA0 * 64 + cb * 8;
        int rB0 = (iL & 31) + ((iL >> 5) + rd * 2) * 64;
        goff[2 + rd] = (long)(n0 + rB0) * Kd + ((cb ^ (rB0 & 7)) << 3);
        doff[2 + rd] = 32768 + rB0 * 64 + cb * 8;
        int rB1 = rB0 + 32;
        goff[4 + rd] = (long)(n0 + rB1) * Kd + ((cb ^ (rB1 & 7)) << 3);
        doff[4 + rd] = 32768 + rB1 * 64 + cb * 8;
        int rA1 = rA0 + 64;
        goff[6 + rd] = (long)(m0 + rA1) * Kd + ((cb ^ (rA1 & 7)) << 3);
        doff[6 + rd] = rA1 * 64 + cb * 8;
    }
    auto stage = [&](int kt, int p, int r) {
        const f16* src = (r == 0 || r == 3) ? A : B;
        #pragma unroll
        for (int rd = 0; rd < 2; ++rd)
            LDS_GL16(src + goff[r * 2 + rd] + kt * 64,
                     lds + p * 16384 + doff[r * 2 + rd]);
    };

    const char* ldsc = (const char*)lds;
    int swz = lr & 7;
    const char* baseA[2], *baseB[2];
    baseA[0] = ldsc + (wm * 128 + lr) * 128 + ((g ^ swz) << 4);
    baseA[1] = ldsc + (wm * 128 + lr) * 128 + (((4 + g) ^ swz) << 4);
    baseB[0] = ldsc + 65536 + (wn * 64 + lr) * 128 + ((g ^ swz) << 4);
    baseB[1] = ldsc + 65536 + (wn * 64 + lr) * 128 + (((4 + g) ^ swz) << 4);

    f32x4 acc[8][4] = {};
    f16x8 a[4][2], b0[2][2], b1[2][2];

    auto loadA = [&](int bufB, int qm) {
        #pragma unroll
        for (int mf = 0; mf < 4; ++mf)
            #pragma unroll
            for (int kk = 0; kk < 2; ++kk)
                a[mf][kk] = *(const f16x8*)(baseA[kk] + bufB + qm * 8192 + mf * 2048);
    };
    auto loadB = [&](f16x8 (&d)[2][2], int bufB, int qn) {
        #pragma unroll
        for (int nf = 0; nf < 2; ++nf)
            #pragma unroll
            for (int kk = 0; kk < 2; ++kk)
                d[nf][kk] = *(const f16x8*)(baseB[kk] + bufB + qn * 4096 + nf * 2048);
    };
    auto mma = [&](f16x8 (&bb)[2][2], int qm, int qn) {
        __builtin_amdgcn_s_setprio(1);
        #pragma unroll
        for (int kk = 0; kk < 2; ++kk)
            #pragma unroll
            for (int mf = 0; mf < 4; ++mf)
                #pragma unroll
                for (int nf = 0; nf < 2; ++nf)
                    acc[qm * 4 + mf][qn * 2 + nf] = __builtin_amdgcn_mfma_f32_16x16x32_f16(
                        a[mf][kk], bb[nf][kk], acc[qm * 4 + mf][qn * 2 + nf], 0, 0, 0);
        __builtin_amdgcn_s_setprio(0);
    };

    int NT = Kd >> 6, NI = NT >> 1;

    stage(0, 0, 0); stage(0, 0, 1); stage(0, 0, 2); stage(0, 0, 3);
    stage(1, 1, 0); stage(1, 1, 1); stage(1, 1, 2);
    VMCNT(6); BAR();                 // tile0 landed; 6 in flight

    for (int it = 0; it < NI - 1; ++it) {
        int t0 = it * 2;
        loadA(0, 0); loadB(b0, 0, 0);
        stage(t0 + 1, 1, 3);
        BAR(); mma(b0, 0, 0); BAR();
        loadB(b1, 0, 1);
        stage(t0 + 2, 0, 0);
        BAR(); mma(b1, 0, 1); BAR();
        loadA(0, 1);
        stage(t0 + 2, 0, 1);
        BAR(); mma(b1, 1, 1); BAR();
        stage(t0 + 2, 0, 2);
        VMCNT(6);                    // tile t0+1 fully landed
        BAR(); mma(b0, 1, 0); BAR();
        loadA(32768, 0); loadB(b0, 32768, 0);
        stage(t0 + 2, 0, 3);
        BAR(); mma(b0, 0, 0); BAR();
        loadB(b1, 32768, 1);
        stage(t0 + 3, 1, 0);
        BAR(); mma(b1, 0, 1); BAR();
        loadA(32768, 1);
        stage(t0 + 3, 1, 1);
        BAR(); mma(b1, 1, 1); BAR();
        stage(t0 + 3, 1, 2);
        VMCNT(6);                    // tile t0+2 fully landed
        BAR(); mma(b0, 1, 0); BAR();
    }
    {   // final iteration (tiles NT-2, NT-1): only p1 stages
        loadA(0, 0); loadB(b0, 0, 0);
        stage(NT - 1, 1, 3);
        BAR(); mma(b0, 0, 0); BAR();
        loadB(b1, 0, 1);
        BAR(); mma(b1, 0, 1); BAR();
        loadA(0, 1);
        BAR(); mma(b1, 1, 1); BAR();
        VMCNT(0);                    // tile NT-1 fully landed
        BAR(); mma(b0, 1, 0); BAR();
        loadA(32768, 0); loadB(b0, 32768, 0);
        BAR(); mma(b0, 0, 0); BAR();
        loadB(b1, 32768, 1);
        BAR(); mma(b1, 0, 1); BAR();
        loadA(32768, 1);
        BAR(); mma(b1, 1, 1); BAR();
        BAR(); mma(b0, 1, 0);
    }

    // ---- epilogue: LDS bounce (XOR de-conflict) -> coalesced stores ----
    __syncthreads();                 // K-loop LDS dead
    if (EPI == 0) {
        #pragma unroll
        for (int i = 0; i < 8; ++i)
            #pragma unroll
            for (int j = 0; j < 4; ++j)
                #pragma unroll
                for (int reg = 0; reg < 4; ++reg) {
                    int row = wm * 128 + i * 16 + g * 4 + reg;
                    int col = (wn * 64 + j * 16 + lr) ^ ((row & 12) << 2);
                    lds[row * 256 + col] = (f16)acc[i][j][reg];
                }
        __syncthreads();
        #pragma unroll
        for (int k = 0; k < 16; ++k) {
            int e = k * 4096 + tid * 8;          // f16 elem in [256][256]
            int row = e >> 8, col = e & 255;
            *(f16x8*)(Ch + (long)(m0 + row) * N + n0 + col) =
                *(const f16x8*)(lds + row * 256 + (col ^ ((row & 12) << 2)));
        }
    } else {
        float* Ct = (float*)lds;                 // [128][256] f32 per pass
        #pragma unroll
        for (int h = 0; h < 2; ++h) {
            if (h) __syncthreads();
            if (wm == h) {
                #pragma unroll
                for (int i = 0; i < 8; ++i)
                    #pragma unroll
                    for (int j = 0; j < 4; ++j)
                        #pragma unroll
                        for (int reg = 0; reg < 4; ++reg) {
                            int row = i * 16 + g * 4 + reg;
                            int col = (wn * 64 + j * 16 + lr) ^ ((row & 4) << 2);
                            Ct[row * 256 + col] = acc[i][j][reg];
                        }
            }
            __syncthreads();
            #pragma unroll
            for (int k = 0; k < 8; ++k) {
                int e = k * 4096 + tid * 8;      // f32 elem in [128][256]
                int row = e >> 8, col = e & 255;
                int pc = col ^ ((row & 4) << 2);
                long gi = (long)(m0 + h * 128 + row) * N + n0 + col;
                float4 c0 = *(const float4*)(Ct + row * 256 + pc);
                float4 c1 = *(const float4*)(Ct + row * 256 + pc + 4);
                float4 r0 = *(const float4*)(resid + gi);
                float4 r1 = *(const float4*)(resid + gi + 4);
                c0.x += r0.x; c0.y += r0.y; c0.z += r0.z; c0.w += r0.w;
                c1.x += r1.x; c1.y += r1.y; c1.z += r1.z; c1.w += r1.w;
                *(float4*)(Cf + gi) = c0;
                *(float4*)(Cf + gi + 4) = c1;
            }
        }
    }
}

// ---- merged q+kv projection: grid 768 (q: 256 blocks, kv: 512 blocks) -----
__global__ __launch_bounds__(512, 2) void gemm_qkv(
        const f16* __restrict__ Aq, const f16* __restrict__ Bq, f16* __restrict__ Cq,
        const f16* __restrict__ Akv, const f16* __restrict__ Bkv, f16* __restrict__ Ckv) {
    int fid = (blockIdx.x & 7) * 96 + (blockIdx.x >> 3);   // XCD swizzle, 768 = 8*96
    const f16 *A, *B; f16* C; int N, lf, sh;
    if (fid < 256) { A = Aq;  B = Bq;  C = Cq;  N = 2048; lf = fid;       sh = 3; }
    else           { A = Akv; B = Bkv; C = Ckv; N = 4096; lf = fid - 256; sh = 4; }
    int by = lf >> sh, bx = lf & ((1 << sh) - 1);
    gemm256_body<0>(A, B, C, nullptr, nullptr, N, 2048, by << 8, bx << 8);
}

// ---- output projection + residual: grid 256 ----
__global__ __launch_bounds__(512, 2) void gemm_out(
        const f16* __restrict__ A, const f16* __restrict__ B,
        float* __restrict__ Cf, const float* __restrict__ resid) {
    int fid = (blockIdx.x & 7) * 32 + (blockIdx.x >> 3);   // 256 = 8*32
    int by = fid >> 3, bx = fid & 7;
    gemm256_body<1>(A, B, nullptr, Cf, resid, 2048, 2048, by << 8, bx << 8);
}

// ---------------- Attention: one block per (b,l,k,h) -----------------------
// V staged TRANSPOSED (Vt[c][k], bank-swizzled) via registers; PV B-frags
// become single ds_read_b128.  Swizzle key s = ((c>>3)^(c&7))&7 applied to
// byte bits [6:4] of the k-offset -> conflict-free on writes AND reads.
__global__ __launch_bounds__(256, 2) void attn_kern(
        const f16* __restrict__ Q,    // [8192, 2048]
        const f16* __restrict__ KV,   // [8192, 4096]  (k | v)
        const float* __restrict__ mask,      // [64*128]
        const float* __restrict__ bias,      // [32*16]
        float* __restrict__ attn_out,        // (B,L,K,H,R,M) f32
        f16* __restrict__ pv_out) {          // [8192, 2048]
    __shared__ f16 Vt[128 * 128];
    __shared__ f16 P[64 * 136];
    int blk = blockIdx.x;
    int h  = blk & 15;
    int bk = blk >> 4;
    int bl = bk >> 1;
    int tid = threadIdx.x, lane = tid & 63, w = tid >> 6;
    int r0 = w << 4;
    int lr = lane & 15, g = lane >> 4;
    long qbase  = (long)bk * 64 * 2048;
    long kvbase = (long)bl * 128 * 4096;
    // issue V loads early (T14): row m = idx>>4, cols c0..c0+7
    f16x8 vreg[8];
    const f16* vsrc = KV + kvbase + 2048 + h * 128;
    #pragma unroll
    for (int rnd = 0; rnd < 8; ++rnd) {
        int idx = tid + rnd * 256;
        vreg[rnd] = *(const f16x8*)(vsrc + (long)(idx >> 4) * 4096 + (idx & 15) * 8);
    }
    // Q fragments
    f16x8 aq[4];
    const f16* qrow = Q + qbase + (long)(r0 + lr) * 2048 + h * 128 + g * 8;
    #pragma unroll
    for (int t4 = 0; t4 < 4; ++t4) aq[t4] = *(const f16x8*)(qrow + t4 * 32);
    // scores S = Q K^T
    f32x4 s[8] = {};
    const f16* kbase = KV + kvbase + h * 128 + g * 8;
    #pragma unroll
    for (int j = 0; j < 8; ++j) {
        #pragma unroll
        for (int t4 = 0; t4 < 4; ++t4) {
            f16x8 bkf = *(const f16x8*)(kbase + (long)(j * 16 + lr) * 4096 + t4 * 32);
            s[j] = __builtin_amdgcn_mfma_f32_16x16x32_f16(aq[t4], bkf, s[j], 0, 0, 0);
        }
    }
    float madd[8];
    #pragma unroll
    for (int j = 0; j < 8; ++j)
        madd[j] = (1.0f - mask[(long)bl * 128 + j * 16 + lr]) * -10000.0f;
    #pragma unroll
    for (int reg = 0; reg < 4; ++reg) {
        int r = r0 + g * 4 + reg;
        float mx = -3.0e38f;
        #pragma unroll
        for (int j = 0; j < 8; ++j) {
            int m = j * 16 + lr;
            int rel = m - r;
            int bkt = (rel < -15 ? -15 : (rel > 16 ? 16 : rel)) + 15;
            float v = s[j][reg] + bias[bkt * 16 + h] + madd[j];
            s[j][reg] = v;
            mx = fmaxf(mx, v);
        }
        #pragma unroll
        for (int d = 1; d < 16; d <<= 1) mx = fmaxf(mx, __shfl_xor(mx, d, 64));
        float sum = 0.0f;
        #pragma unroll
        for (int j = 0; j < 8; ++j) {
            float e = __expf(s[j][reg] - mx);
            s[j][reg] = e;
            sum += e;
        }
        #pragma unroll
        for (int d = 1; d < 16; d <<= 1) sum += __shfl_xor(sum, d, 64);
        float inv = 1.0f / sum;
        #pragma unroll
        for (int j = 0; j < 8; ++j) s[j][reg] *= inv;
    }
    long abase = (long)blk * 64 * 128;
    #pragma unroll
    for (int reg = 0; reg < 4; ++reg) {
        int r = r0 + g * 4 + reg;
        #pragma unroll
        for (int j = 0; j < 8; ++j) {
            attn_out[abase + (long)r * 128 + j * 16 + lr] = s[j][reg];
            P[r * 136 + j * 16 + lr] = (f16)s[j][reg];
        }
    }
    // write Vt (transposed, swizzled): Vt[c][k] = V[k][c]
    {
        char* vtb = (char*)Vt;
        #pragma unroll
        for (int rnd = 0; rnd < 8; ++rnd) {
            int idx = tid + rnd * 256;
            int k = idx >> 4, c0 = (idx & 15) * 8;
            #pragma unroll
            for (int i = 0; i < 8; ++i) {
                int c = c0 + i;
                int sx = ((c >> 3) ^ i) & 7;               // c&7 == i
                *(f16*)(vtb + c * 256 + ((k * 2) ^ (sx << 4))) = vreg[rnd][i];
            }
        }
    }
    __syncthreads();
    // PV: out[64,128] = P[64,128] * V[128,128]  (bv = Vt b128 reads)
    f16x8 pa[4];
    #pragma unroll
    for (int t4 = 0; t4 < 4; ++t4)
        pa[t4] = *(const f16x8*)(P + (r0 + lr) * 136 + t4 * 32 + g * 8);
    f32x4 o[8] = {};
    const char* vtb = (const char*)Vt;
    #pragma unroll
    for (int dj = 0; dj < 8; ++dj) {
        int c = dj * 16 + lr;
        int sc = (((c >> 3) ^ (c & 7)) & 7) << 4;
        const char* vrow = vtb + c * 256;
        #pragma unroll
        for (int t4 = 0; t4 < 4; ++t4) {
            f16x8 bv = *(const f16x8*)(vrow + ((t4 * 64 + g * 16) ^ sc));
            o[dj] = __builtin_amdgcn_mfma_f32_16x16x32_f16(pa[t4], bv, o[dj], 0, 0, 0);
        }
    }
    // bounce o through Vt (dead) with XOR de-conflict -> coalesced stores
    __syncthreads();
    #pragma unroll
    for (int dj = 0; dj < 8; ++dj)
        #pragma unroll
        for (int reg = 0; reg < 4; ++reg) {
            int row = r0 + g * 4 + reg;
            int col = (dj * 16 + lr) ^ ((row & 12) << 2);
            Vt[row * 128 + col] = (f16)o[dj][reg];
        }
    __syncthreads();
    f16* ob = pv_out + qbase + h * 128;
    #pragma unroll
    for (int k = 0; k < 4; ++k) {
        int e = k * 2048 + tid * 8;              // f16 elem in [64][128]
        int row = e >> 7, col = e & 127;
        *(f16x8*)(ob + (long)row * 2048 + col) =
            *(const f16x8*)(Vt + row * 128 + (col ^ ((row & 12) << 2)));
    }
}

extern "C" void kernel_launch(void* const* d_in, const int* in_sizes, int n_in,
                              void* d_out, int out_size, void* d_ws, size_t ws_size,
                              hipStream_t stream) {
    const float* x     = (const float*)d_in[0];
    const float* hid   = (const float*)d_in[1];
    const float* mask  = (const float*)d_in[2];
    const float* lnsc  = (const float*)d_in[3];
    const float* q_w   = (const float*)d_in[4];
    const float* kv_w  = (const float*)d_in[5];
    const float* out_w = (const float*)d_in[6];
    const float* bias  = (const float*)d_in[7];
    float* out0 = (float*)d_out;             // (B,L,K,R,Dm) = 16,777,216 f32
    float* attn = out0 + 16777216;           // (B,L,K,H,R,M) = 16,777,216 f32

    // Scratch aliased into dead d_out regions (lifetimes stream-ordered):
    f16* kv_h  = (f16*)out0;                 // dead until final GEMM
    f16* xn_h  = (f16*)attn;                 // dead until attn_kern writes attn
    f16* hid_h = (f16*)(attn + 8388608);
    char* ws = (char*)d_ws;
    f16* q_h    = (f16*)(ws);                 // 32 MiB
    f16* ao_h   = (f16*)(ws + 33554432L);     // 32 MiB
    f16* qw_h   = (f16*)(ws + 67108864L);     //  8 MiB
    f16* kvw_h  = (f16*)(ws + 75497472L);     // 16 MiB
    f16* outw_h = (f16*)(ws + 92274688L);     //  8 MiB -> 96 MiB total

    prep_kern<<<24576, 256, 0, stream>>>(q_w, qw_h, kv_w, kvw_h,
                                         out_w, outw_h, hid, hid_h,
                                         x, lnsc, xn_h);
    gemm_qkv<<<768, 512, 0, stream>>>(xn_h, qw_h, q_h, hid_h, kvw_h, kv_h);
    attn_kern<<<2048, 256, 0, stream>>>(q_h, kv_h, mask, bias, attn, ao_h);
    gemm_out<<<256, 512, 0, stream>>>(ao_h, outw_h, out0, x);
}

// Round 9
// 369.718 us; speedup vs baseline: 1.3040x; 1.0009x over previous
//
#include <hip/hip_runtime.h>

typedef _Float16 f16;
typedef _Float16 f16x8 __attribute__((ext_vector_type(8)));
typedef float f32x4 __attribute__((ext_vector_type(4)));

#define LDS_GL16(g, l) __builtin_amdgcn_global_load_lds( \
    (const __attribute__((address_space(1))) void*)(g),  \
    (__attribute__((address_space(3))) void*)(l), 16, 0, 0)
#define VMCNT(N) asm volatile("s_waitcnt vmcnt(" #N ")" ::: "memory")
#define BAR() __builtin_amdgcn_s_barrier()

// ---- fused prep: f32->f16 converts (4 bufs) + RMSNorm, one launch ---------
__global__ __launch_bounds__(256) void prep_kern(
        const float* __restrict__ qw,   f16* __restrict__ qwh,
        const float* __restrict__ kvw,  f16* __restrict__ kvwh,
        const float* __restrict__ outw, f16* __restrict__ outwh,
        const float* __restrict__ hid,  f16* __restrict__ hidh,
        const float* __restrict__ x, const float* __restrict__ lnsc,
        f16* __restrict__ xnh) {
    int b = blockIdx.x;
    if (b >= 16384) {   // RMSNorm row
        long base = (long)(b - 16384) * 2048 + threadIdx.x * 8;
        float4 a = *(const float4*)(x + base);
        float4 v = *(const float4*)(x + base + 4);
        float ss = a.x*a.x + a.y*a.y + a.z*a.z + a.w*a.w
                 + v.x*v.x + v.y*v.y + v.z*v.z + v.w*v.w;
        #pragma unroll
        for (int d = 1; d < 64; d <<= 1) ss += __shfl_xor(ss, d, 64);
        __shared__ float red[4];
        if ((threadIdx.x & 63) == 0) red[threadIdx.x >> 6] = ss;
        __syncthreads();
        ss = red[0] + red[1] + red[2] + red[3];
        float inv = 1.0f / (sqrtf(ss * (1.0f / 2048.0f)) + 1e-8f);
        int c = threadIdx.x * 8;
        float4 s1 = *(const float4*)(lnsc + c);
        float4 s2 = *(const float4*)(lnsc + c + 4);
        f16x8 o = { (f16)(a.x*inv*s1.x),(f16)(a.y*inv*s1.y),(f16)(a.z*inv*s1.z),(f16)(a.w*inv*s1.w),
                    (f16)(v.x*inv*s2.x),(f16)(v.y*inv*s2.y),(f16)(v.z*inv*s2.z),(f16)(v.w*inv*s2.w) };
        *(f16x8*)(xnh + base) = o;
        return;
    }
    const float* in; f16* out; long base;
    if (b < 2048)       { in = qw;   out = qwh;   base = (long)b * 2048; }
    else if (b < 6144)  { in = kvw;  out = kvwh;  base = (long)(b - 2048) * 2048; }
    else if (b < 8192)  { in = outw; out = outwh; base = (long)(b - 6144) * 2048; }
    else                { in = hid;  out = hidh;  base = (long)(b - 8192) * 2048; }
    long o = base + threadIdx.x * 8;
    float4 a = *(const float4*)(in + o);
    float4 c = *(const float4*)(in + o + 4);
    f16x8 v = { (f16)a.x,(f16)a.y,(f16)a.z,(f16)a.w,
                (f16)c.x,(f16)c.y,(f16)c.z,(f16)c.w };
    *(f16x8*)(out + o) = v;
}

// ---------------- GEMM 256x256 body, BK=64, 8 waves, 8-phase pipelined -----
// C[M,N] = A[M,K] * B[N,K]^T.  EPI=0: f16 out. EPI=1: f32 out + resid.
// b0 (held B quadrant) is PRE-loaded at p4/p8 post-mma (buffer landed by that
// phase's VMCNT) -> ds_read distribution 8/4/8/4 instead of 12/4/8/0.
template<int EPI>
__device__ __forceinline__ void gemm256_body(
        const f16* __restrict__ A, const f16* __restrict__ B,
        f16* __restrict__ Ch, float* __restrict__ Cf,
        const float* __restrict__ resid, int N, int Kd, int m0, int n0) {
    alignas(16) __shared__ f16 lds[65536];
    int tid = threadIdx.x, lane = tid & 63;
    int wid = tid >> 6, wm = wid >> 2, wn = wid & 3;
    int lr = lane & 15, g = lane >> 4;
    int iL = tid >> 3, cb = tid & 7;

    long goff[8]; int doff[8];
    #pragma unroll
    for (int rd = 0; rd < 2; ++rd) {
        int rA0 = iL + rd * 128;
        goff[0 + rd] = (long)(m0 + rA0) * Kd + ((cb ^ (rA0 & 7)) << 3);
        doff[0 + rd] = rA0 * 64 + cb * 8;
        int rB0 = (iL & 31) + ((iL >> 5) + rd * 2) * 64;
        goff[2 + rd] = (long)(n0 + rB0) * Kd + ((cb ^ (rB0 & 7)) << 3);
        doff[2 + rd] = 32768 + rB0 * 64 + cb * 8;
        int rB1 = rB0 + 32;
        goff[4 + rd] = (long)(n0 + rB1) * Kd + ((cb ^ (rB1 & 7)) << 3);
        doff[4 + rd] = 32768 + rB1 * 64 + cb * 8;
        int rA1 = rA0 + 64;
        goff[6 + rd] = (long)(m0 + rA1) * Kd + ((cb ^ (rA1 & 7)) << 3);
        doff[6 + rd] = rA1 * 64 + cb * 8;
    }
    auto stage = [&](int kt, int p, int r) {
        const f16* src = (r == 0 || r == 3) ? A : B;
        #pragma unroll
        for (int rd = 0; rd < 2; ++rd)
            LDS_GL16(src + goff[r * 2 + rd] + kt * 64,
                     lds + p * 16384 + doff[r * 2 + rd]);
    };

    const char* ldsc = (const char*)lds;
    int swz = lr & 7;
    const char* baseA[2], *baseB[2];
    baseA[0] = ldsc + (wm * 128 + lr) * 128 + ((g ^ swz) << 4);
    baseA[1] = ldsc + (wm * 128 + lr) * 128 + (((4 + g) ^ swz) << 4);
    baseB[0] = ldsc + 65536 + (wn * 64 + lr) * 128 + ((g ^ swz) << 4);
    baseB[1] = ldsc + 65536 + (wn * 64 + lr) * 128 + (((4 + g) ^ swz) << 4);

    f32x4 acc[8][4] = {};
    f16x8 a[4][2], b0[2][2], b1[2][2];

    auto loadA = [&](int bufB, int qm) {
        #pragma unroll
        for (int mf = 0; mf < 4; ++mf)
            #pragma unroll
            for (int kk = 0; kk < 2; ++kk)
                a[mf][kk] = *(const f16x8*)(baseA[kk] + bufB + qm * 8192 + mf * 2048);
    };
    auto loadB = [&](f16x8 (&d)[2][2], int bufB, int qn) {
        #pragma unroll
        for (int nf = 0; nf < 2; ++nf)
            #pragma unroll
            for (int kk = 0; kk < 2; ++kk)
                d[nf][kk] = *(const f16x8*)(baseB[kk] + bufB + qn * 4096 + nf * 2048);
    };
    auto mma = [&](f16x8 (&bb)[2][2], int qm, int qn) {
        __builtin_amdgcn_s_setprio(1);
        #pragma unroll
        for (int kk = 0; kk < 2; ++kk)
            #pragma unroll
            for (int mf = 0; mf < 4; ++mf)
                #pragma unroll
                for (int nf = 0; nf < 2; ++nf)
                    acc[qm * 4 + mf][qn * 2 + nf] = __builtin_amdgcn_mfma_f32_16x16x32_f16(
                        a[mf][kk], bb[nf][kk], acc[qm * 4 + mf][qn * 2 + nf], 0, 0, 0);
        __builtin_amdgcn_s_setprio(0);
    };

    int NT = Kd >> 6, NI = NT >> 1;

    stage(0, 0, 0); stage(0, 0, 1); stage(0, 0, 2); stage(0, 0, 3);
    stage(1, 1, 0); stage(1, 1, 1); stage(1, 1, 2);
    VMCNT(6); BAR();                 // tile0 landed; 6 in flight
    loadB(b0, 0, 0);                 // preload b0 for first p1

    for (int it = 0; it < NI - 1; ++it) {
        int t0 = it * 2;
        // p1
        loadA(0, 0);
        stage(t0 + 1, 1, 3);
        BAR(); mma(b0, 0, 0); BAR();
        // p2
        loadB(b1, 0, 1);
        stage(t0 + 2, 0, 0);
        BAR(); mma(b1, 0, 1); BAR();
        // p3
        loadA(0, 1);
        stage(t0 + 2, 0, 1);
        BAR(); mma(b1, 1, 1); BAR();
        // p4: mma(b0 held), then preload b0 for p5 (buf1 landed at VMCNT)
        stage(t0 + 2, 0, 2);
        VMCNT(6);                    // tile t0+1 fully landed
        BAR(); mma(b0, 1, 0); loadB(b0, 32768, 0); BAR();
        // p5
        loadA(32768, 0);
        stage(t0 + 2, 0, 3);
        BAR(); mma(b0, 0, 0); BAR();
        // p6
        loadB(b1, 32768, 1);
        stage(t0 + 3, 1, 0);
        BAR(); mma(b1, 0, 1); BAR();
        // p7
        loadA(32768, 1);
        stage(t0 + 3, 1, 1);
        BAR(); mma(b1, 1, 1); BAR();
        // p8: mma(b0 held), preload b0 for next p1 (buf0 t0+2 landed)
        stage(t0 + 3, 1, 2);
        VMCNT(6);                    // tile t0+2 fully landed
        BAR(); mma(b0, 1, 0); loadB(b0, 0, 0); BAR();
    }
    {   // final iteration (tiles NT-2, NT-1)
        loadA(0, 0);
        stage(NT - 1, 1, 3);
        BAR(); mma(b0, 0, 0); BAR();
        loadB(b1, 0, 1);
        BAR(); mma(b1, 0, 1); BAR();
        loadA(0, 1);
        BAR(); mma(b1, 1, 1); BAR();
        VMCNT(0);                    // tile NT-1 fully landed
        BAR(); mma(b0, 1, 0); loadB(b0, 32768, 0); BAR();
        loadA(32768, 0);
        BAR(); mma(b0, 0, 0); BAR();
        loadB(b1, 32768, 1);
        BAR(); mma(b1, 0, 1); BAR();
        loadA(32768, 1);
        BAR(); mma(b1, 1, 1); BAR();
        BAR(); mma(b0, 1, 0);
    }

    // ---- epilogue: LDS bounce (XOR de-conflict) -> coalesced stores ----
    __syncthreads();                 // K-loop LDS dead
    if (EPI == 0) {
        #pragma unroll
        for (int i = 0; i < 8; ++i)
            #pragma unroll
            for (int j = 0; j < 4; ++j)
                #pragma unroll
                for (int reg = 0; reg < 4; ++reg) {
                    int row = wm * 128 + i * 16 + g * 4 + reg;
                    int col = (wn * 64 + j * 16 + lr) ^ ((row & 12) << 2);
                    lds[row * 256 + col] = (f16)acc[i][j][reg];
                }
        __syncthreads();
        #pragma unroll
        for (int k = 0; k < 16; ++k) {
            int e = k * 4096 + tid * 8;          // f16 elem in [256][256]
            int row = e >> 8, col = e & 255;
            *(f16x8*)(Ch + (long)(m0 + row) * N + n0 + col) =
                *(const f16x8*)(lds + row * 256 + (col ^ ((row & 12) << 2)));
        }
    } else {
        float* Ct = (float*)lds;                 // [128][256] f32 per pass
        #pragma unroll
        for (int h = 0; h < 2; ++h) {
            if (h) __syncthreads();
            if (wm == h) {
                #pragma unroll
                for (int i = 0; i < 8; ++i)
                    #pragma unroll
                    for (int j = 0; j < 4; ++j)
                        #pragma unroll
                        for (int reg = 0; reg < 4; ++reg) {
                            int row = i * 16 + g * 4 + reg;
                            int col = (wn * 64 + j * 16 + lr) ^ ((row & 4) << 2);
                            Ct[row * 256 + col] = acc[i][j][reg];
                        }
            }
            // issue resid loads BEFORE the barrier: latency hides under
            // barrier wait + LDS read-back
            float4 ra[8], rb[8];
            #pragma unroll
            for (int k = 0; k < 8; ++k) {
                int e = k * 4096 + tid * 8;
                int row = e >> 8, col = e & 255;
                long gi = (long)(m0 + h * 128 + row) * N + n0 + col;
                ra[k] = *(const float4*)(resid + gi);
                rb[k] = *(const float4*)(resid + gi + 4);
            }
            __syncthreads();
            #pragma unroll
            for (int k = 0; k < 8; ++k) {
                int e = k * 4096 + tid * 8;      // f32 elem in [128][256]
                int row = e >> 8, col = e & 255;
                int pc = col ^ ((row & 4) << 2);
                long gi = (long)(m0 + h * 128 + row) * N + n0 + col;
                float4 c0 = *(const float4*)(Ct + row * 256 + pc);
                float4 c1 = *(const float4*)(Ct + row * 256 + pc + 4);
                c0.x += ra[k].x; c0.y += ra[k].y; c0.z += ra[k].z; c0.w += ra[k].w;
                c1.x += rb[k].x; c1.y += rb[k].y; c1.z += rb[k].z; c1.w += rb[k].w;
                *(float4*)(Cf + gi) = c0;
                *(float4*)(Cf + gi + 4) = c1;
            }
        }
    }
}

// ---- merged q+kv projection: grid 768 (q: 256 blocks, kv: 512 blocks) -----
__global__ __launch_bounds__(512, 2) void gemm_qkv(
        const f16* __restrict__ Aq, const f16* __restrict__ Bq, f16* __restrict__ Cq,
        const f16* __restrict__ Akv, const f16* __restrict__ Bkv, f16* __restrict__ Ckv) {
    int fid = (blockIdx.x & 7) * 96 + (blockIdx.x >> 3);   // XCD swizzle, 768 = 8*96
    const f16 *A, *B; f16* C; int N, lf, sh;
    if (fid < 256) { A = Aq;  B = Bq;  C = Cq;  N = 2048; lf = fid;       sh = 3; }
    else           { A = Akv; B = Bkv; C = Ckv; N = 4096; lf = fid - 256; sh = 4; }
    int by = lf >> sh, bx = lf & ((1 << sh) - 1);
    gemm256_body<0>(A, B, C, nullptr, nullptr, N, 2048, by << 8, bx << 8);
}

// ---- output projection + residual: grid 256 ----
__global__ __launch_bounds__(512, 2) void gemm_out(
        const f16* __restrict__ A, const f16* __restrict__ B,
        float* __restrict__ Cf, const float* __restrict__ resid) {
    int fid = (blockIdx.x & 7) * 32 + (blockIdx.x >> 3);   // 256 = 8*32
    int by = fid >> 3, bx = fid & 7;
    gemm256_body<1>(A, B, nullptr, Cf, resid, 2048, 2048, by << 8, bx << 8);
}

// ---------------- Attention: one block per (b,l,k,h) -----------------------
__global__ __launch_bounds__(256, 2) void attn_kern(
        const f16* __restrict__ Q,    // [8192, 2048]
        const f16* __restrict__ KV,   // [8192, 4096]  (k | v)
        const float* __restrict__ mask,      // [64*128]
        const float* __restrict__ bias,      // [32*16]
        float* __restrict__ attn_out,        // (B,L,K,H,R,M) f32
        f16* __restrict__ pv_out) {          // [8192, 2048]
    __shared__ f16 Vt[128 * 128];
    __shared__ f16 P[64 * 136];
    int blk = blockIdx.x;
    int h  = blk & 15;
    int bk = blk >> 4;
    int bl = bk >> 1;
    int tid = threadIdx.x, lane = tid & 63, w = tid >> 6;
    int r0 = w << 4;
    int lr = lane & 15, g = lane >> 4;
    long qbase  = (long)bk * 64 * 2048;
    long kvbase = (long)bl * 128 * 4096;
    f16x8 vreg[8];
    const f16* vsrc = KV + kvbase + 2048 + h * 128;
    #pragma unroll
    for (int rnd = 0; rnd < 8; ++rnd) {
        int idx = tid + rnd * 256;
        vreg[rnd] = *(const f16x8*)(vsrc + (long)(idx >> 4) * 4096 + (idx & 15) * 8);
    }
    f16x8 aq[4];
    const f16* qrow = Q + qbase + (long)(r0 + lr) * 2048 + h * 128 + g * 8;
    #pragma unroll
    for (int t4 = 0; t4 < 4; ++t4) aq[t4] = *(const f16x8*)(qrow + t4 * 32);
    f32x4 s[8] = {};
    const f16* kbase = KV + kvbase + h * 128 + g * 8;
    #pragma unroll
    for (int j = 0; j < 8; ++j) {
        #pragma unroll
        for (int t4 = 0; t4 < 4; ++t4) {
            f16x8 bkf = *(const f16x8*)(kbase + (long)(j * 16 + lr) * 4096 + t4 * 32);
            s[j] = __builtin_amdgcn_mfma_f32_16x16x32_f16(aq[t4], bkf, s[j], 0, 0, 0);
        }
    }
    float madd[8];
    #pragma unroll
    for (int j = 0; j < 8; ++j)
        madd[j] = (1.0f - mask[(long)bl * 128 + j * 16 + lr]) * -10000.0f;
    #pragma unroll
    for (int reg = 0; reg < 4; ++reg) {
        int r = r0 + g * 4 + reg;
        float mx = -3.0e38f;
        #pragma unroll
        for (int j = 0; j < 8; ++j) {
            int m = j * 16 + lr;
            int rel = m - r;
            int bkt = (rel < -15 ? -15 : (rel > 16 ? 16 : rel)) + 15;
            float v = s[j][reg] + bias[bkt * 16 + h] + madd[j];
            s[j][reg] = v;
            mx = fmaxf(mx, v);
        }
        #pragma unroll
        for (int d = 1; d < 16; d <<= 1) mx = fmaxf(mx, __shfl_xor(mx, d, 64));
        float sum = 0.0f;
        #pragma unroll
        for (int j = 0; j < 8; ++j) {
            float e = __expf(s[j][reg] - mx);
            s[j][reg] = e;
            sum += e;
        }
        #pragma unroll
        for (int d = 1; d < 16; d <<= 1) sum += __shfl_xor(sum, d, 64);
        float inv = 1.0f / sum;
        #pragma unroll
        for (int j = 0; j < 8; ++j) s[j][reg] *= inv;
    }
    long abase = (long)blk * 64 * 128;
    #pragma unroll
    for (int reg = 0; reg < 4; ++reg) {
        int r = r0 + g * 4 + reg;
        #pragma unroll
        for (int j = 0; j < 8; ++j) {
            attn_out[abase + (long)r * 128 + j * 16 + lr] = s[j][reg];
            P[r * 136 + j * 16 + lr] = (f16)s[j][reg];
        }
    }
    {
        char* vtb = (char*)Vt;
        #pragma unroll
        for (int rnd = 0; rnd < 8; ++rnd) {
            int idx = tid + rnd * 256;
            int k = idx >> 4, c0 = (idx & 15) * 8;
            #pragma unroll
            for (int i = 0; i < 8; ++i) {
                int c = c0 + i;
                int sx = ((c >> 3) ^ i) & 7;
                *(f16*)(vtb + c * 256 + ((k * 2) ^ (sx << 4))) = vreg[rnd][i];
            }
        }
    }
    __syncthreads();
    f16x8 pa[4];
    #pragma unroll
    for (int t4 = 0; t4 < 4; ++t4)
        pa[t4] = *(const f16x8*)(P + (r0 + lr) * 136 + t4 * 32 + g * 8);
    f32x4 o[8] = {};
    const char* vtb = (const char*)Vt;
    #pragma unroll
    for (int dj = 0; dj < 8; ++dj) {
        int c = dj * 16 + lr;
        int sc = (((c >> 3) ^ (c & 7)) & 7) << 4;
        const char* vrow = vtb + c * 256;
        #pragma unroll
        for (int t4 = 0; t4 < 4; ++t4) {
            f16x8 bv = *(const f16x8*)(vrow + ((t4 * 64 + g * 16) ^ sc));
            o[dj] = __builtin_amdgcn_mfma_f32_16x16x32_f16(pa[t4], bv, o[dj], 0, 0, 0);
        }
    }
    __syncthreads();
    #pragma unroll
    for (int dj = 0; dj < 8; ++dj)
        #pragma unroll
        for (int reg = 0; reg < 4; ++reg) {
            int row = r0 + g * 4 + reg;
            int col = (dj * 16 + lr) ^ ((row & 12) << 2);
            Vt[row * 128 + col] = (f16)o[dj][reg];
        }
    __syncthreads();
    f16* ob = pv_out + qbase + h * 128;
    #pragma unroll
    for (int k = 0; k < 4; ++k) {
        int e = k * 2048 + tid * 8;
        int row = e >> 7, col = e & 127;
        *(f16x8*)(ob + (long)row * 2048 + col) =
            *(const f16x8*)(Vt + row * 128 + (col ^ ((row & 12) << 2)));
    }
}

extern "C" void kernel_launch(void* const* d_in, const int* in_sizes, int n_in,
                              void* d_out, int out_size, void* d_ws, size_t ws_size,
                              hipStream_t stream) {
    const float* x     = (const float*)d_in[0];
    const float* hid   = (const float*)d_in[1];
    const float* mask  = (const float*)d_in[2];
    const float* lnsc  = (const float*)d_in[3];
    const float* q_w   = (const float*)d_in[4];
    const float* kv_w  = (const float*)d_in[5];
    const float* out_w = (const float*)d_in[6];
    const float* bias  = (const float*)d_in[7];
    float* out0 = (float*)d_out;             // (B,L,K,R,Dm) = 16,777,216 f32
    float* attn = out0 + 16777216;           // (B,L,K,H,R,M) = 16,777,216 f32

    f16* kv_h  = (f16*)out0;                 // dead until final GEMM
    f16* xn_h  = (f16*)attn;                 // dead until attn_kern writes attn
    f16* hid_h = (f16*)(attn + 8388608);
    char* ws = (char*)d_ws;
    f16* q_h    = (f16*)(ws);                 // 32 MiB
    f16* ao_h   = (f16*)(ws + 33554432L);     // 32 MiB
    f16* qw_h   = (f16*)(ws + 67108864L);     //  8 MiB
    f16* kvw_h  = (f16*)(ws + 75497472L);     // 16 MiB
    f16* outw_h = (f16*)(ws + 92274688L);     //  8 MiB -> 96 MiB total

    prep_kern<<<24576, 256, 0, stream>>>(q_w, qw_h, kv_w, kvw_h,
                                         out_w, outw_h, hid, hid_h,
                                         x, lnsc, xn_h);
    gemm_qkv<<<768, 512, 0, stream>>>(xn_h, qw_h, q_h, hid_h, kvw_h, kv_h);
    attn_kern<<<2048, 256, 0, stream>>>(q_h, kv_h, mask, bias, attn, ao_h);
    gemm_out<<<256, 512, 0, stream>>>(ao_h, outw_h, out0, x);
}